// Round 1
// baseline (2331.646 us; speedup 1.0000x reference)
//
#include <hip/hip_runtime.h>
#include <hip/hip_bf16.h>

__device__ __forceinline__ float lrelu(float x, float s) { return x > 0.f ? x : x * s; }

// atomic float max via monotonic int/uint trick; requires init to -inf
__device__ __forceinline__ void atomicMaxF(float* addr, float val) {
  if (val >= 0.f) atomicMax((int*)addr, __float_as_int(val));
  else            atomicMin((unsigned int*)addr, __float_as_uint(val));
}

__global__ void init_kernel(float* __restrict__ emax, float* __restrict__ esum,
                            float* __restrict__ agg, int n_att, int n_agg) {
  int i = blockIdx.x * blockDim.x + threadIdx.x;
  int stride = gridDim.x * blockDim.x;
  for (int j = i; j < n_att; j += stride) { emax[j] = -__builtin_inff(); esum[j] = 0.f; }
  for (int j = i; j < n_agg; j += stride) agg[j] = 0.f;
}

// H = act(In (+bias_in, lrelu 0.01)) @ W ;  a_src/a_dst = per-head attention dots.
// In: [n,128], W: [128,128] row-major. 8 nodes per block-iteration.
// thread t: node_local = t>>5, cols [4*(t&31), +4)
template<int HEADS>
__global__ void __launch_bounds__(256)
feat_kernel(const float* __restrict__ In, const float* __restrict__ W,
            const float* __restrict__ att_s, const float* __restrict__ att_d,
            const float* __restrict__ bias_in,
            float* __restrict__ Hout, float* __restrict__ a_src, float* __restrict__ a_dst,
            int n)
{
  __shared__ float Wc[32 * 128];   // 16 KB W chunk
  __shared__ float xs[8][128];     // 4 KB node rows
  const int t = threadIdx.x;
  const int nl = t >> 5;
  const int l32 = t & 31;
  const int c0 = l32 * 4;
  const int iters = (n + 7) >> 3;
  for (int it = blockIdx.x; it < iters; it += gridDim.x) {
    const int nbase = it << 3;
    __syncthreads();   // previous iteration's xs reads done
    {
      const int r = t >> 5, o = (t & 31) << 2;
      const int node = nbase + r;
      float4 v = make_float4(0.f, 0.f, 0.f, 0.f);
      if (node < n) {
        v = *(const float4*)&In[(size_t)node * 128 + o];
        if (bias_in) {
          const float4 b = *(const float4*)&bias_in[o];
          v.x = lrelu(v.x + b.x, 0.01f); v.y = lrelu(v.y + b.y, 0.01f);
          v.z = lrelu(v.z + b.z, 0.01f); v.w = lrelu(v.w + b.w, 0.01f);
        }
      }
      *(float4*)&xs[r][o] = v;
    }
    float accx = 0.f, accy = 0.f, accz = 0.f, accw = 0.f;
    for (int kc = 0; kc < 4; ++kc) {
      __syncthreads();  // prev chunk's Wc reads done (also covers xs writes on kc==0)
      #pragma unroll
      for (int i = 0; i < 4; ++i)
        ((float4*)Wc)[t + i * 256] = ((const float4*)W)[kc * 1024 + t + i * 256];
      __syncthreads();
      #pragma unroll
      for (int kk = 0; kk < 32; ++kk) {
        const float xv = xs[nl][kc * 32 + kk];
        const float4 wv = *(const float4*)&Wc[kk * 128 + c0];
        accx += xv * wv.x; accy += xv * wv.y; accz += xv * wv.z; accw += xv * wv.w;
      }
    }
    const int node = nbase + nl;
    const float4 as = *(const float4*)&att_s[c0];
    const float4 ad = *(const float4*)&att_d[c0];
    float ps = accx * as.x + accy * as.y + accz * as.z + accw * as.w;
    float pd = accx * ad.x + accy * ad.y + accz * ad.z + accw * ad.w;
    const int GROUP = (HEADS == 8) ? 4 : 32;   // lanes per head-group (C/4)
    #pragma unroll
    for (int off = 1; off < GROUP; off <<= 1) {
      ps += __shfl_xor(ps, off);
      pd += __shfl_xor(pd, off);
    }
    if (node < n) {
      *(float4*)&Hout[(size_t)node * 128 + c0] = make_float4(accx, accy, accz, accw);
      if ((l32 & (GROUP - 1)) == 0) {
        const int h = (HEADS == 8) ? (l32 >> 2) : 0;
        a_src[node * HEADS + h] = ps;
        a_dst[node * HEADS + h] = pd;
      }
    }
  }
}

template<int HEADS>
__global__ void edge_max_kernel(const int* __restrict__ esrc, const int* __restrict__ edst,
                                const float* __restrict__ a_src, const float* __restrict__ a_dst,
                                float* __restrict__ emax, int E, int Etot)
{
  const int idx = blockIdx.x * blockDim.x + threadIdx.x;
  if (idx >= Etot * HEADS) return;
  const int e = idx / HEADS, h = idx % HEADS;
  int s, d;
  if (e < E) { s = esrc[e]; d = edst[e]; } else { s = e - E; d = s; }
  const float v = lrelu(a_src[s * HEADS + h] + a_dst[d * HEADS + h], 0.2f);
  atomicMaxF(&emax[d * HEADS + h], v);
}

template<int HEADS>
__global__ void edge_sum_kernel(const int* __restrict__ esrc, const int* __restrict__ edst,
                                const float* __restrict__ a_src, const float* __restrict__ a_dst,
                                const float* __restrict__ emax, float* __restrict__ esum,
                                int E, int Etot)
{
  const int idx = blockIdx.x * blockDim.x + threadIdx.x;
  if (idx >= Etot * HEADS) return;
  const int e = idx / HEADS, h = idx % HEADS;
  int s, d;
  if (e < E) { s = esrc[e]; d = edst[e]; } else { s = e - E; d = s; }
  const float v = lrelu(a_src[s * HEADS + h] + a_dst[d * HEADS + h], 0.2f);
  const float ee = __expf(v - emax[d * HEADS + h]);
  atomicAdd(&esum[d * HEADS + h], ee);
}

// one wave per edge; lane covers features lane and lane+64
template<int HEADS>
__global__ void __launch_bounds__(256)
edge_agg_kernel(const int* __restrict__ esrc, const int* __restrict__ edst,
                const float* __restrict__ a_src, const float* __restrict__ a_dst,
                const float* __restrict__ emax, const float* __restrict__ esum,
                const float* __restrict__ Hf, float* __restrict__ agg, int E, int Etot)
{
  const int wave = threadIdx.x >> 6;
  const int lane = threadIdx.x & 63;
  const int e = blockIdx.x * 4 + wave;
  if (e >= Etot) return;
  int s, d;
  if (e < E) { s = esrc[e]; d = edst[e]; } else { s = e - E; d = s; }
  float alpha_mine = 0.f;
  if (lane < HEADS) {
    const float v = lrelu(a_src[s * HEADS + lane] + a_dst[d * HEADS + lane], 0.2f);
    const float ee = __expf(v - emax[d * HEADS + lane]);
    alpha_mine = ee / (esum[d * HEADS + lane] + 1e-16f);
  }
  const float h0 = Hf[(size_t)s * 128 + lane];
  const float h1 = Hf[(size_t)s * 128 + 64 + lane];
  const float al0 = __shfl(alpha_mine, (HEADS == 8) ? (lane >> 4) : 0);
  const float al1 = __shfl(alpha_mine, (HEADS == 8) ? ((lane + 64) >> 4) : 0);
  atomicAdd(&agg[(size_t)d * 128 + lane], h0 * al0);
  atomicAdd(&agg[(size_t)d * 128 + 64 + lane], h1 * al1);
}

// out[n,k] = cos(mu[k], (agg2[n]+b2) @ g[:, k*64 .. k*64+64))
// block: 512 threads = 8 waves; wave = k, lane = m; 16 nodes per block
__global__ void __launch_bounds__(512)
final_kernel(const float* __restrict__ agg2, const float* __restrict__ b2,
             const float* __restrict__ g, const float* __restrict__ mu,
             float* __restrict__ outp, int n)
{
  __shared__ float os[16][128];
  const int t = threadIdx.x;
  const int k = t >> 6;
  const int m = t & 63;
  const int nbase = blockIdx.x << 4;
  {
    const int r = t >> 5, o = (t & 31) << 2;
    const int node = nbase + r;
    float4 v = make_float4(0.f, 0.f, 0.f, 0.f);
    if (node < n) {
      v = *(const float4*)&agg2[(size_t)node * 128 + o];
      const float4 b = *(const float4*)&b2[o];
      v.x += b.x; v.y += b.y; v.z += b.z; v.w += b.w;
    }
    *(float4*)&os[r][o] = v;
  }
  __syncthreads();
  float acc[16];
  #pragma unroll
  for (int i = 0; i < 16; ++i) acc[i] = 0.f;
  const int c = t;  // column 0..511 of g
  for (int f = 0; f < 128; f += 4) {
    const float g0 = g[(size_t)(f + 0) * 512 + c];
    const float g1 = g[(size_t)(f + 1) * 512 + c];
    const float g2 = g[(size_t)(f + 2) * 512 + c];
    const float g3 = g[(size_t)(f + 3) * 512 + c];
    #pragma unroll
    for (int i = 0; i < 16; ++i) {
      const float4 ov = *(const float4*)&os[i][f];
      acc[i] += ov.x * g0 + ov.y * g1 + ov.z * g2 + ov.w * g3;
    }
  }
  const float muv = mu[k * 64 + m];
  float munsq = muv * muv;
  #pragma unroll
  for (int off = 1; off < 64; off <<= 1) munsq += __shfl_xor(munsq, off);
  const float mun = fmaxf(sqrtf(munsq), 1e-8f);
  #pragma unroll
  for (int i = 0; i < 16; ++i) {
    const float v = acc[i];
    float num = muv * v;
    float ss = v * v;
    #pragma unroll
    for (int off = 1; off < 64; off <<= 1) {
      num += __shfl_xor(num, off);
      ss += __shfl_xor(ss, off);
    }
    const int node = nbase + i;
    if (m == 0 && node < n) {
      const float den = mun * fmaxf(sqrtf(ss), 1e-8f);
      outp[(size_t)node * 8 + k] = num / den;
    }
  }
}

extern "C" void kernel_launch(void* const* d_in, const int* in_sizes, int n_in,
                              void* d_out, int out_size, void* d_ws, size_t ws_size,
                              hipStream_t stream)
{
  const float* x   = (const float*)d_in[0];
  const int*   eix = (const int*)d_in[1];
  const float* W1  = (const float*)d_in[2];
  const float* as1 = (const float*)d_in[3];
  const float* ad1 = (const float*)d_in[4];
  const float* b1  = (const float*)d_in[5];
  const float* W2  = (const float*)d_in[6];
  const float* as2 = (const float*)d_in[7];
  const float* ad2 = (const float*)d_in[8];
  const float* b2  = (const float*)d_in[9];
  const float* g   = (const float*)d_in[10];
  const float* mu  = (const float*)d_in[11];
  float* outp = (float*)d_out;

  const int n    = in_sizes[0] / 128;
  const int E    = in_sizes[1] / 2;
  const int Etot = E + n;                 // with self-loops appended
  const int* esrc = eix;
  const int* edst = eix + E;

  // workspace layout (floats): hbuf[n*128] aggbuf[n*128] asrc[n*8] adst[n*8] emax[n*8] esum[n*8]
  float* hbuf   = (float*)d_ws;
  float* aggbuf = hbuf   + (size_t)n * 128;
  float* asrc   = aggbuf + (size_t)n * 128;
  float* adst   = asrc   + (size_t)n * 8;
  float* emax   = adst   + (size_t)n * 8;
  float* esum   = emax   + (size_t)n * 8;

  // ---------------- conv1 (heads=8, C=16) ----------------
  init_kernel<<<2048, 256, 0, stream>>>(emax, esum, aggbuf, n * 8, n * 128);
  feat_kernel<8><<<1024, 256, 0, stream>>>(x, W1, as1, ad1, nullptr, hbuf, asrc, adst, n);
  {
    const int tot = Etot * 8;
    edge_max_kernel<8><<<(tot + 255) / 256, 256, 0, stream>>>(esrc, edst, asrc, adst, emax, E, Etot);
    edge_sum_kernel<8><<<(tot + 255) / 256, 256, 0, stream>>>(esrc, edst, asrc, adst, emax, esum, E, Etot);
  }
  edge_agg_kernel<8><<<(Etot + 3) / 4, 256, 0, stream>>>(esrc, edst, asrc, adst, emax, esum, hbuf, aggbuf, E, Etot);

  // ---------------- conv2 (heads=1, C=128) ----------------
  // input = lrelu(aggbuf + b1, 0.01); writes h2 into hbuf (h1 is dead)
  feat_kernel<1><<<1024, 256, 0, stream>>>(aggbuf, W2, as2, ad2, b1, hbuf, asrc, adst, n);
  init_kernel<<<2048, 256, 0, stream>>>(emax, esum, aggbuf, n, n * 128);
  edge_max_kernel<1><<<(Etot + 255) / 256, 256, 0, stream>>>(esrc, edst, asrc, adst, emax, E, Etot);
  edge_sum_kernel<1><<<(Etot + 255) / 256, 256, 0, stream>>>(esrc, edst, asrc, adst, emax, esum, E, Etot);
  edge_agg_kernel<1><<<(Etot + 3) / 4, 256, 0, stream>>>(esrc, edst, asrc, adst, emax, esum, hbuf, aggbuf, E, Etot);

  // ---------------- h@g + cosine vs mu ----------------
  final_kernel<<<(n + 15) / 16, 512, 0, stream>>>(aggbuf, b2, g, mu, outp, n);
}

// Round 2
// 1157.565 us; speedup vs baseline: 2.0143x; 2.0143x over previous
//
#include <hip/hip_runtime.h>
#include <hip/hip_bf16.h>

__device__ __forceinline__ float lrelu(float x, float s) { return x > 0.f ? x : x * s; }

// ---------------- CSR build ----------------
__global__ void deg_init_kernel(int* __restrict__ deg, int n) {
  int i = blockIdx.x * blockDim.x + threadIdx.x;
  if (i < n) deg[i] = 1;   // self-loop
}

__global__ void deg_count_kernel(const int* __restrict__ edst, int* __restrict__ deg, int E) {
  int i = blockIdx.x * blockDim.x + threadIdx.x;
  if (i < E) atomicAdd(&deg[edst[i]], 1);
}

// block scans 2048 elements (256 threads x 8); writes local exclusive-scan value
// and per-block totals.
__global__ void __launch_bounds__(256)
scan1_kernel(const int* __restrict__ deg, int* __restrict__ out,
             int* __restrict__ blksum, int n) {
  __shared__ int ts[256];
  const int t = threadIdx.x;
  const int base = blockIdx.x * 2048 + t * 8;
  int v[8]; int s = 0;
  #pragma unroll
  for (int i = 0; i < 8; ++i) {
    int x = (base + i < n) ? deg[base + i] : 0;
    v[i] = s; s += x;
  }
  ts[t] = s;
  __syncthreads();
  for (int off = 1; off < 256; off <<= 1) {
    int add = (t >= off) ? ts[t - off] : 0;
    __syncthreads();
    ts[t] += add;
    __syncthreads();
  }
  const int excl = ts[t] - s;   // exclusive prefix of this thread within block
  #pragma unroll
  for (int i = 0; i < 8; ++i)
    if (base + i < n) out[base + i] = excl + v[i];
  if (t == 255) blksum[blockIdx.x] = ts[255];
}

// single wave scans block totals (nb <= 64) -> inclusive
__global__ void scan2_kernel(int* __restrict__ blksum, int nb) {
  const int t = threadIdx.x;
  int v = (t < nb) ? blksum[t] : 0;
  #pragma unroll
  for (int off = 1; off < 64; off <<= 1) {
    int u = __shfl_up(v, off);
    if (t >= off) v += u;
  }
  if (t < nb) blksum[t] = v;
}

__global__ void scan3_kernel(int* __restrict__ out, const int* __restrict__ blksum, int n) {
  int i = blockIdx.x * blockDim.x + threadIdx.x;
  if (i >= n) return;
  int b = i >> 11;
  if (b > 0) out[i] += blksum[b - 1];
}

// scatter edges into col[]; rowptr starts as exclusive offsets and ends as END offsets
__global__ void scatter_kernel(const int* __restrict__ esrc, const int* __restrict__ edst,
                               int* __restrict__ rowptr, int* __restrict__ col,
                               int E, int n) {
  int i = blockIdx.x * blockDim.x + threadIdx.x;
  if (i < E) {
    int s = esrc[i], d = edst[i];
    int p = atomicAdd(&rowptr[d], 1);
    col[p] = s;
  } else if (i < E + n) {
    int d = i - E;
    int p = atomicAdd(&rowptr[d], 1);
    col[p] = d;   // self-loop
  }
}

// ---------------- features + attention dots ----------------
// H = act(In (+bias_in, lrelu 0.01)) @ W ;  a_src/a_dst = per-head attention dots.
template<int HEADS>
__global__ void __launch_bounds__(256)
feat_kernel(const float* __restrict__ In, const float* __restrict__ W,
            const float* __restrict__ att_s, const float* __restrict__ att_d,
            const float* __restrict__ bias_in,
            float* __restrict__ Hout, float* __restrict__ a_src, float* __restrict__ a_dst,
            int n)
{
  __shared__ float Wc[32 * 128];
  __shared__ float xs[8][128];
  const int t = threadIdx.x;
  const int nl = t >> 5;
  const int l32 = t & 31;
  const int c0 = l32 * 4;
  const int iters = (n + 7) >> 3;
  for (int it = blockIdx.x; it < iters; it += gridDim.x) {
    const int nbase = it << 3;
    __syncthreads();
    {
      const int r = t >> 5, o = (t & 31) << 2;
      const int node = nbase + r;
      float4 v = make_float4(0.f, 0.f, 0.f, 0.f);
      if (node < n) {
        v = *(const float4*)&In[(size_t)node * 128 + o];
        if (bias_in) {
          const float4 b = *(const float4*)&bias_in[o];
          v.x = lrelu(v.x + b.x, 0.01f); v.y = lrelu(v.y + b.y, 0.01f);
          v.z = lrelu(v.z + b.z, 0.01f); v.w = lrelu(v.w + b.w, 0.01f);
        }
      }
      *(float4*)&xs[r][o] = v;
    }
    float accx = 0.f, accy = 0.f, accz = 0.f, accw = 0.f;
    for (int kc = 0; kc < 4; ++kc) {
      __syncthreads();
      #pragma unroll
      for (int i = 0; i < 4; ++i)
        ((float4*)Wc)[t + i * 256] = ((const float4*)W)[kc * 1024 + t + i * 256];
      __syncthreads();
      #pragma unroll
      for (int kk = 0; kk < 32; ++kk) {
        const float xv = xs[nl][kc * 32 + kk];
        const float4 wv = *(const float4*)&Wc[kk * 128 + c0];
        accx += xv * wv.x; accy += xv * wv.y; accz += xv * wv.z; accw += xv * wv.w;
      }
    }
    const int node = nbase + nl;
    const float4 as = *(const float4*)&att_s[c0];
    const float4 ad = *(const float4*)&att_d[c0];
    float ps = accx * as.x + accy * as.y + accz * as.z + accw * as.w;
    float pd = accx * ad.x + accy * ad.y + accz * ad.z + accw * ad.w;
    const int GROUP = (HEADS == 8) ? 4 : 32;
    #pragma unroll
    for (int off = 1; off < GROUP; off <<= 1) {
      ps += __shfl_xor(ps, off);
      pd += __shfl_xor(pd, off);
    }
    if (node < n) {
      *(float4*)&Hout[(size_t)node * 128 + c0] = make_float4(accx, accy, accz, accw);
      if ((l32 & (GROUP - 1)) == 0) {
        const int h = (HEADS == 8) ? (l32 >> 2) : 0;
        a_src[node * HEADS + h] = ps;
        a_dst[node * HEADS + h] = pd;
      }
    }
  }
}

// ---------------- CSR gather-aggregate (softmax fused) ----------------
// one wave per destination node
template<int HEADS>
__global__ void __launch_bounds__(256)
agg_csr_kernel(const int* __restrict__ rowptr_end, const int* __restrict__ col,
               const float* __restrict__ a_src, const float* __restrict__ a_dst,
               const float* __restrict__ Hf, float* __restrict__ agg, int n)
{
  const int wave = threadIdx.x >> 6;
  const int lane = threadIdx.x & 63;
  const int d = blockIdx.x * 4 + wave;
  if (d >= n) return;
  const int beg = (d == 0) ? 0 : rowptr_end[d - 1];
  const int end = rowptr_end[d];

  if (HEADS == 8) {
    const int h  = lane & 7;    // head for the reduce passes
    const int ei = lane >> 3;   // edge slot 0..7
    const float adv = a_dst[d * 8 + h];
    float m = -__builtin_inff();
    for (int p = beg + ei; p < end; p += 8) {
      const int s = col[p];
      m = fmaxf(m, lrelu(a_src[s * 8 + h] + adv, 0.2f));
    }
    m = fmaxf(m, __shfl_xor(m, 8));
    m = fmaxf(m, __shfl_xor(m, 16));
    m = fmaxf(m, __shfl_xor(m, 32));
    float sum = 0.f;
    for (int p = beg + ei; p < end; p += 8) {
      const int s = col[p];
      sum += __expf(lrelu(a_src[s * 8 + h] + adv, 0.2f) - m);
    }
    sum += __shfl_xor(sum, 8);
    sum += __shfl_xor(sum, 16);
    sum += __shfl_xor(sum, 32);
    // lane covers features lane (head lane>>4) and lane+64 (head (lane>>4)+4)
    const int h0 = lane >> 4, h1 = h0 + 4;
    const float m0 = __shfl(m, h0), s0 = __shfl(sum, h0);
    const float m1 = __shfl(m, h1), s1 = __shfl(sum, h1);
    const float ad0 = a_dst[d * 8 + h0], ad1 = a_dst[d * 8 + h1];
    float acc0 = 0.f, acc1 = 0.f;
    for (int p = beg; p < end; ++p) {
      const int s = col[p];
      const float al0 = __expf(lrelu(a_src[s * 8 + h0] + ad0, 0.2f) - m0) / (s0 + 1e-16f);
      const float al1 = __expf(lrelu(a_src[s * 8 + h1] + ad1, 0.2f) - m1) / (s1 + 1e-16f);
      acc0 += al0 * Hf[(size_t)s * 128 + lane];
      acc1 += al1 * Hf[(size_t)s * 128 + 64 + lane];
    }
    agg[(size_t)d * 128 + lane]      = acc0;
    agg[(size_t)d * 128 + 64 + lane] = acc1;
  } else {
    const float adv = a_dst[d];
    float m = -__builtin_inff();
    for (int p = beg + lane; p < end; p += 64)
      m = fmaxf(m, lrelu(a_src[col[p]] + adv, 0.2f));
    #pragma unroll
    for (int off = 1; off < 64; off <<= 1) m = fmaxf(m, __shfl_xor(m, off));
    float sum = 0.f;
    for (int p = beg + lane; p < end; p += 64)
      sum += __expf(lrelu(a_src[col[p]] + adv, 0.2f) - m);
    #pragma unroll
    for (int off = 1; off < 64; off <<= 1) sum += __shfl_xor(sum, off);
    const float inv = 1.f / (sum + 1e-16f);
    float acc0 = 0.f, acc1 = 0.f;
    for (int p = beg; p < end; ++p) {
      const int s = col[p];
      const float al = __expf(lrelu(a_src[s] + adv, 0.2f) - m) * inv;
      acc0 += al * Hf[(size_t)s * 128 + lane];
      acc1 += al * Hf[(size_t)s * 128 + 64 + lane];
    }
    agg[(size_t)d * 128 + lane]      = acc0;
    agg[(size_t)d * 128 + 64 + lane] = acc1;
  }
}

// ---------------- h@g + cosine vs mu ----------------
__global__ void __launch_bounds__(512)
final_kernel(const float* __restrict__ agg2, const float* __restrict__ b2,
             const float* __restrict__ g, const float* __restrict__ mu,
             float* __restrict__ outp, int n)
{
  __shared__ float os[16][128];
  const int t = threadIdx.x;
  const int k = t >> 6;
  const int m = t & 63;
  const int nbase = blockIdx.x << 4;
  {
    const int r = t >> 5, o = (t & 31) << 2;
    const int node = nbase + r;
    float4 v = make_float4(0.f, 0.f, 0.f, 0.f);
    if (node < n) {
      v = *(const float4*)&agg2[(size_t)node * 128 + o];
      const float4 b = *(const float4*)&b2[o];
      v.x += b.x; v.y += b.y; v.z += b.z; v.w += b.w;
    }
    *(float4*)&os[r][o] = v;
  }
  __syncthreads();
  float acc[16];
  #pragma unroll
  for (int i = 0; i < 16; ++i) acc[i] = 0.f;
  const int c = t;
  for (int f = 0; f < 128; f += 4) {
    const float g0 = g[(size_t)(f + 0) * 512 + c];
    const float g1 = g[(size_t)(f + 1) * 512 + c];
    const float g2 = g[(size_t)(f + 2) * 512 + c];
    const float g3 = g[(size_t)(f + 3) * 512 + c];
    #pragma unroll
    for (int i = 0; i < 16; ++i) {
      const float4 ov = *(const float4*)&os[i][f];
      acc[i] += ov.x * g0 + ov.y * g1 + ov.z * g2 + ov.w * g3;
    }
  }
  const float muv = mu[k * 64 + m];
  float munsq = muv * muv;
  #pragma unroll
  for (int off = 1; off < 64; off <<= 1) munsq += __shfl_xor(munsq, off);
  const float mun = fmaxf(sqrtf(munsq), 1e-8f);
  #pragma unroll
  for (int i = 0; i < 16; ++i) {
    const float v = acc[i];
    float num = muv * v;
    float ss = v * v;
    #pragma unroll
    for (int off = 1; off < 64; off <<= 1) {
      num += __shfl_xor(num, off);
      ss += __shfl_xor(ss, off);
    }
    const int node = nbase + i;
    if (m == 0 && node < n) {
      const float den = mun * fmaxf(sqrtf(ss), 1e-8f);
      outp[(size_t)node * 8 + k] = num / den;
    }
  }
}

extern "C" void kernel_launch(void* const* d_in, const int* in_sizes, int n_in,
                              void* d_out, int out_size, void* d_ws, size_t ws_size,
                              hipStream_t stream)
{
  const float* x   = (const float*)d_in[0];
  const int*   eix = (const int*)d_in[1];
  const float* W1  = (const float*)d_in[2];
  const float* as1 = (const float*)d_in[3];
  const float* ad1 = (const float*)d_in[4];
  const float* b1  = (const float*)d_in[5];
  const float* W2  = (const float*)d_in[6];
  const float* as2 = (const float*)d_in[7];
  const float* ad2 = (const float*)d_in[8];
  const float* b2  = (const float*)d_in[9];
  const float* g   = (const float*)d_in[10];
  const float* mu  = (const float*)d_in[11];
  float* outp = (float*)d_out;

  const int n    = in_sizes[0] / 128;
  const int E    = in_sizes[1] / 2;
  const int Etot = E + n;
  const int* esrc = eix;
  const int* edst = eix + E;

  // workspace layout:
  //   hbuf[n*128] f | aggbuf[n*128] f | asrc[n*8] f | adst[n*8] f | rowptr[n] i | col[Etot] i
  // deg + blksum alias the aggbuf region during CSR build (aggbuf first written later).
  float* hbuf   = (float*)d_ws;
  float* aggbuf = hbuf   + (size_t)n * 128;
  float* asrc   = aggbuf + (size_t)n * 128;
  float* adst   = asrc   + (size_t)n * 8;
  int*   rowptr = (int*)(adst + (size_t)n * 8);
  int*   col    = rowptr + n;
  int*   deg    = (int*)aggbuf;
  int*   blksum = deg + n;

  // ---------------- CSR build (by destination, self-loops included) ----------------
  const int nb = (n + 2047) / 2048;
  deg_init_kernel<<<(n + 255) / 256, 256, 0, stream>>>(deg, n);
  deg_count_kernel<<<(E + 255) / 256, 256, 0, stream>>>(edst, deg, E);
  scan1_kernel<<<nb, 256, 0, stream>>>(deg, rowptr, blksum, n);
  scan2_kernel<<<1, 64, 0, stream>>>(blksum, nb);
  scan3_kernel<<<(n + 255) / 256, 256, 0, stream>>>(rowptr, blksum, n);
  scatter_kernel<<<(Etot + 255) / 256, 256, 0, stream>>>(esrc, edst, rowptr, col, E, n);

  // ---------------- conv1 (heads=8, C=16) ----------------
  feat_kernel<8><<<1024, 256, 0, stream>>>(x, W1, as1, ad1, nullptr, hbuf, asrc, adst, n);
  agg_csr_kernel<8><<<(n + 3) / 4, 256, 0, stream>>>(rowptr, col, asrc, adst, hbuf, aggbuf, n);

  // ---------------- conv2 (heads=1, C=128) ----------------
  feat_kernel<1><<<1024, 256, 0, stream>>>(aggbuf, W2, as2, ad2, b1, hbuf, asrc, adst, n);
  agg_csr_kernel<1><<<(n + 3) / 4, 256, 0, stream>>>(rowptr, col, asrc, adst, hbuf, aggbuf, n);

  // ---------------- h@g + cosine vs mu ----------------
  final_kernel<<<(n + 15) / 16, 512, 0, stream>>>(aggbuf, b2, g, mu, outp, n);
}

// Round 3
// 896.667 us; speedup vs baseline: 2.6003x; 1.2910x over previous
//
#include <hip/hip_runtime.h>
#include <hip/hip_bf16.h>

__device__ __forceinline__ float lrelu(float x, float s) { return x > 0.f ? x : x * s; }

// ---------------- CSR build ----------------
__global__ void deg_init_kernel(int* __restrict__ deg, int n) {
  int i = blockIdx.x * blockDim.x + threadIdx.x;
  if (i < n) deg[i] = 1;   // self-loop
}

__global__ void deg_count_kernel(const int* __restrict__ edst, int* __restrict__ deg, int E) {
  int i = blockIdx.x * blockDim.x + threadIdx.x;
  if (i < E) atomicAdd(&deg[edst[i]], 1);
}

__global__ void __launch_bounds__(256)
scan1_kernel(const int* __restrict__ deg, int* __restrict__ out,
             int* __restrict__ blksum, int n) {
  __shared__ int ts[256];
  const int t = threadIdx.x;
  const int base = blockIdx.x * 2048 + t * 8;
  int v[8]; int s = 0;
  #pragma unroll
  for (int i = 0; i < 8; ++i) {
    int x = (base + i < n) ? deg[base + i] : 0;
    v[i] = s; s += x;
  }
  ts[t] = s;
  __syncthreads();
  for (int off = 1; off < 256; off <<= 1) {
    int add = (t >= off) ? ts[t - off] : 0;
    __syncthreads();
    ts[t] += add;
    __syncthreads();
  }
  const int excl = ts[t] - s;
  #pragma unroll
  for (int i = 0; i < 8; ++i)
    if (base + i < n) out[base + i] = excl + v[i];
  if (t == 255) blksum[blockIdx.x] = ts[255];
}

__global__ void scan2_kernel(int* __restrict__ blksum, int nb) {
  const int t = threadIdx.x;
  int v = (t < nb) ? blksum[t] : 0;
  #pragma unroll
  for (int off = 1; off < 64; off <<= 1) {
    int u = __shfl_up(v, off);
    if (t >= off) v += u;
  }
  if (t < nb) blksum[t] = v;
}

__global__ void scan3_kernel(int* __restrict__ out, const int* __restrict__ blksum, int n) {
  int i = blockIdx.x * blockDim.x + threadIdx.x;
  if (i >= n) return;
  int b = i >> 11;
  if (b > 0) out[i] += blksum[b - 1];
}

__global__ void scatter_kernel(const int* __restrict__ esrc, const int* __restrict__ edst,
                               int* __restrict__ rowptr, int* __restrict__ col,
                               int E, int n) {
  int i = blockIdx.x * blockDim.x + threadIdx.x;
  if (i < E) {
    int s = esrc[i], d = edst[i];
    int p = atomicAdd(&rowptr[d], 1);
    col[p] = s;
  } else if (i < E + n) {
    int d = i - E;
    int p = atomicAdd(&rowptr[d], 1);
    col[p] = d;
  }
}

// ---------------- features + attention dots ----------------
template<int HEADS>
__global__ void __launch_bounds__(256)
feat_kernel(const float* __restrict__ In, const float* __restrict__ W,
            const float* __restrict__ att_s, const float* __restrict__ att_d,
            const float* __restrict__ bias_in,
            float* __restrict__ Hout, float* __restrict__ a_src, float* __restrict__ a_dst,
            int n)
{
  __shared__ float Wc[32 * 128];
  __shared__ float xs[8][128];
  const int t = threadIdx.x;
  const int nl = t >> 5;
  const int l32 = t & 31;
  const int c0 = l32 * 4;
  const int iters = (n + 7) >> 3;
  for (int it = blockIdx.x; it < iters; it += gridDim.x) {
    const int nbase = it << 3;
    __syncthreads();
    {
      const int r = t >> 5, o = (t & 31) << 2;
      const int node = nbase + r;
      float4 v = make_float4(0.f, 0.f, 0.f, 0.f);
      if (node < n) {
        v = *(const float4*)&In[(size_t)node * 128 + o];
        if (bias_in) {
          const float4 b = *(const float4*)&bias_in[o];
          v.x = lrelu(v.x + b.x, 0.01f); v.y = lrelu(v.y + b.y, 0.01f);
          v.z = lrelu(v.z + b.z, 0.01f); v.w = lrelu(v.w + b.w, 0.01f);
        }
      }
      *(float4*)&xs[r][o] = v;
    }
    float accx = 0.f, accy = 0.f, accz = 0.f, accw = 0.f;
    for (int kc = 0; kc < 4; ++kc) {
      __syncthreads();
      #pragma unroll
      for (int i = 0; i < 4; ++i)
        ((float4*)Wc)[t + i * 256] = ((const float4*)W)[kc * 1024 + t + i * 256];
      __syncthreads();
      #pragma unroll
      for (int kk = 0; kk < 32; ++kk) {
        const float xv = xs[nl][kc * 32 + kk];
        const float4 wv = *(const float4*)&Wc[kk * 128 + c0];
        accx += xv * wv.x; accy += xv * wv.y; accz += xv * wv.z; accw += xv * wv.w;
      }
    }
    const int node = nbase + nl;
    const float4 as = *(const float4*)&att_s[c0];
    const float4 ad = *(const float4*)&att_d[c0];
    float ps = accx * as.x + accy * as.y + accz * as.z + accw * as.w;
    float pd = accx * ad.x + accy * ad.y + accz * ad.z + accw * ad.w;
    const int GROUP = (HEADS == 8) ? 4 : 32;
    #pragma unroll
    for (int off = 1; off < GROUP; off <<= 1) {
      ps += __shfl_xor(ps, off);
      pd += __shfl_xor(pd, off);
    }
    if (node < n) {
      *(float4*)&Hout[(size_t)node * 128 + c0] = make_float4(accx, accy, accz, accw);
      if ((l32 & (GROUP - 1)) == 0) {
        const int h = (HEADS == 8) ? (l32 >> 2) : 0;
        a_src[node * HEADS + h] = ps;
        a_dst[node * HEADS + h] = pd;
      }
    }
  }
}

// ---------------- CSR gather-aggregate (softmax fused) ----------------
// one wave per destination node; alpha computed once per (edge,head), broadcast by shuffle
template<int HEADS>
__global__ void __launch_bounds__(256)
agg_csr_kernel(const int* __restrict__ rowptr_end, const int* __restrict__ col,
               const float* __restrict__ a_src, const float* __restrict__ a_dst,
               const float* __restrict__ Hf, float* __restrict__ agg, int n)
{
  const int wave = threadIdx.x >> 6;
  const int lane = threadIdx.x & 63;
  const int d = blockIdx.x * 4 + wave;
  if (d >= n) return;
  const int beg = (d == 0) ? 0 : rowptr_end[d - 1];
  const int end = rowptr_end[d];
  float accx = 0.f, accy = 0.f;

  if (HEADS == 8) {
    const int h  = lane & 7;    // head this lane computes alphas for
    const int ei = lane >> 3;   // edge slot 0..7
    const int hf = lane >> 3;   // head of this lane's feature pair (feats 2*lane, 2*lane+1)
    const float adv = a_dst[d * 8 + h];
    float m = -__builtin_inff();
    for (int p = beg + ei; p < end; p += 8)
      m = fmaxf(m, lrelu(a_src[col[p] * 8 + h] + adv, 0.2f));
    m = fmaxf(m, __shfl_xor(m, 8));
    m = fmaxf(m, __shfl_xor(m, 16));
    m = fmaxf(m, __shfl_xor(m, 32));
    float sum = 0.f;
    for (int p = beg + ei; p < end; p += 8)
      sum += __expf(lrelu(a_src[col[p] * 8 + h] + adv, 0.2f) - m);
    sum += __shfl_xor(sum, 8);
    sum += __shfl_xor(sum, 16);
    sum += __shfl_xor(sum, 32);
    const float inv = 1.f / (sum + 1e-16f);
    for (int p0 = beg; p0 < end; p0 += 8) {
      const int cnt = min(8, end - p0);
      int sv = 0; float a = 0.f;
      if (ei < cnt) {
        sv = col[p0 + ei];
        a = __expf(lrelu(a_src[sv * 8 + h] + adv, 0.2f) - m) * inv;
      }
      for (int e = 0; e < cnt; ++e) {
        const float al = __shfl(a, e * 8 + hf);
        const int   s  = __shfl(sv, e * 8);
        const float2 hv = *(const float2*)&Hf[(size_t)s * 128 + lane * 2];
        accx += al * hv.x; accy += al * hv.y;
      }
    }
  } else {
    const float adv = a_dst[d];
    float m = -__builtin_inff();
    for (int p = beg + lane; p < end; p += 64)
      m = fmaxf(m, lrelu(a_src[col[p]] + adv, 0.2f));
    #pragma unroll
    for (int off = 1; off < 64; off <<= 1) m = fmaxf(m, __shfl_xor(m, off));
    float sum = 0.f;
    for (int p = beg + lane; p < end; p += 64)
      sum += __expf(lrelu(a_src[col[p]] + adv, 0.2f) - m);
    #pragma unroll
    for (int off = 1; off < 64; off <<= 1) sum += __shfl_xor(sum, off);
    const float inv = 1.f / (sum + 1e-16f);
    for (int p0 = beg; p0 < end; p0 += 64) {
      const int cnt = min(64, end - p0);
      int sv = 0; float a = 0.f;
      if (lane < cnt) {
        sv = col[p0 + lane];
        a = __expf(lrelu(a_src[sv] + adv, 0.2f) - m) * inv;
      }
      for (int e = 0; e < cnt; ++e) {
        const float al = __shfl(a, e);
        const int   s  = __shfl(sv, e);
        const float2 hv = *(const float2*)&Hf[(size_t)s * 128 + lane * 2];
        accx += al * hv.x; accy += al * hv.y;
      }
    }
  }
  *(float2*)&agg[(size_t)d * 128 + lane * 2] = make_float2(accx, accy);
}

// ---------------- h@g + cosine vs mu (register-tiled f32 GEMM) ----------------
// block = 256 threads / 4 waves; tile = 32 nodes x 512 cols; thread owns 8x8
__global__ void __launch_bounds__(256, 2)
final_kernel(const float* __restrict__ agg2, const float* __restrict__ b2,
             const float* __restrict__ g, const float* __restrict__ mu,
             float* __restrict__ outp, int n)
{
  __shared__ float os[32][128];
  const int t = threadIdx.x;
  const int wave = t >> 6;
  const int lane = t & 63;
  const int nbase = blockIdx.x << 5;
  #pragma unroll
  for (int i = 0; i < 4; ++i) {
    const int q = t + i * 256;
    const int r = q >> 5, o = (q & 31) << 2;
    const int node = nbase + r;
    float4 v = make_float4(0.f, 0.f, 0.f, 0.f);
    if (node < n) {
      v = *(const float4*)&agg2[(size_t)node * 128 + o];
      const float4 b = *(const float4*)&b2[o];
      v.x += b.x; v.y += b.y; v.z += b.z; v.w += b.w;
    }
    *(float4*)&os[r][o] = v;
  }
  __syncthreads();

  const int r0 = wave * 8;
  const int c0 = lane * 8;
  float acc[8][8];
  #pragma unroll
  for (int r = 0; r < 8; ++r)
    #pragma unroll
    for (int c = 0; c < 8; ++c) acc[r][c] = 0.f;

  for (int k0 = 0; k0 < 128; k0 += 4) {
    float4 ga[4], gb[4];
    #pragma unroll
    for (int kk = 0; kk < 4; ++kk) {
      ga[kk] = *(const float4*)&g[(size_t)(k0 + kk) * 512 + c0];
      gb[kk] = *(const float4*)&g[(size_t)(k0 + kk) * 512 + c0 + 4];
    }
    float4 ov[8];
    #pragma unroll
    for (int r = 0; r < 8; ++r) ov[r] = *(const float4*)&os[r0 + r][k0];
    #pragma unroll
    for (int r = 0; r < 8; ++r) {
      #pragma unroll
      for (int kk = 0; kk < 4; ++kk) {
        const float o = (kk == 0) ? ov[r].x : (kk == 1) ? ov[r].y : (kk == 2) ? ov[r].z : ov[r].w;
        acc[r][0] += o * ga[kk].x;
        acc[r][1] += o * ga[kk].y;
        acc[r][2] += o * ga[kk].z;
        acc[r][3] += o * ga[kk].w;
        acc[r][4] += o * gb[kk].x;
        acc[r][5] += o * gb[kk].y;
        acc[r][6] += o * gb[kk].z;
        acc[r][7] += o * gb[kk].w;
      }
    }
  }

  // epilogue: cosine vs mu. col c0+c maps directly to mu[c0+c]; k-group = lane>>3.
  float mus[8];
  #pragma unroll
  for (int c = 0; c < 8; ++c) mus[c] = mu[c0 + c];
  float munsq = 0.f;
  #pragma unroll
  for (int c = 0; c < 8; ++c) munsq += mus[c] * mus[c];
  munsq += __shfl_xor(munsq, 1);
  munsq += __shfl_xor(munsq, 2);
  munsq += __shfl_xor(munsq, 4);
  const float mun = fmaxf(sqrtf(munsq), 1e-8f);
  const int kgrp = lane >> 3;
  #pragma unroll
  for (int r = 0; r < 8; ++r) {
    float num = 0.f, ss = 0.f;
    #pragma unroll
    for (int c = 0; c < 8; ++c) {
      num += mus[c] * acc[r][c];
      ss  += acc[r][c] * acc[r][c];
    }
    num += __shfl_xor(num, 1); ss += __shfl_xor(ss, 1);
    num += __shfl_xor(num, 2); ss += __shfl_xor(ss, 2);
    num += __shfl_xor(num, 4); ss += __shfl_xor(ss, 4);
    const int node = nbase + r0 + r;
    if ((lane & 7) == 0 && node < n) {
      const float den = mun * fmaxf(sqrtf(ss), 1e-8f);
      outp[(size_t)node * 8 + kgrp] = num / den;
    }
  }
}

extern "C" void kernel_launch(void* const* d_in, const int* in_sizes, int n_in,
                              void* d_out, int out_size, void* d_ws, size_t ws_size,
                              hipStream_t stream)
{
  const float* x   = (const float*)d_in[0];
  const int*   eix = (const int*)d_in[1];
  const float* W1  = (const float*)d_in[2];
  const float* as1 = (const float*)d_in[3];
  const float* ad1 = (const float*)d_in[4];
  const float* b1  = (const float*)d_in[5];
  const float* W2  = (const float*)d_in[6];
  const float* as2 = (const float*)d_in[7];
  const float* ad2 = (const float*)d_in[8];
  const float* b2  = (const float*)d_in[9];
  const float* g   = (const float*)d_in[10];
  const float* mu  = (const float*)d_in[11];
  float* outp = (float*)d_out;

  const int n    = in_sizes[0] / 128;
  const int E    = in_sizes[1] / 2;
  const int Etot = E + n;
  const int* esrc = eix;
  const int* edst = eix + E;

  float* hbuf   = (float*)d_ws;
  float* aggbuf = hbuf   + (size_t)n * 128;
  float* asrc   = aggbuf + (size_t)n * 128;
  float* adst   = asrc   + (size_t)n * 8;
  int*   rowptr = (int*)(adst + (size_t)n * 8);
  int*   col    = rowptr + n;
  int*   deg    = (int*)aggbuf;
  int*   blksum = deg + n;

  // ---------------- CSR build (by destination, self-loops included) ----------------
  const int nb = (n + 2047) / 2048;
  deg_init_kernel<<<(n + 255) / 256, 256, 0, stream>>>(deg, n);
  deg_count_kernel<<<(E + 255) / 256, 256, 0, stream>>>(edst, deg, E);
  scan1_kernel<<<nb, 256, 0, stream>>>(deg, rowptr, blksum, n);
  scan2_kernel<<<1, 64, 0, stream>>>(blksum, nb);
  scan3_kernel<<<(n + 255) / 256, 256, 0, stream>>>(rowptr, blksum, n);
  scatter_kernel<<<(Etot + 255) / 256, 256, 0, stream>>>(esrc, edst, rowptr, col, E, n);

  // ---------------- conv1 (heads=8, C=16) ----------------
  feat_kernel<8><<<1024, 256, 0, stream>>>(x, W1, as1, ad1, nullptr, hbuf, asrc, adst, n);
  agg_csr_kernel<8><<<(n + 3) / 4, 256, 0, stream>>>(rowptr, col, asrc, adst, hbuf, aggbuf, n);

  // ---------------- conv2 (heads=1, C=128) ----------------
  feat_kernel<1><<<1024, 256, 0, stream>>>(aggbuf, W2, as2, ad2, b1, hbuf, asrc, adst, n);
  agg_csr_kernel<1><<<(n + 3) / 4, 256, 0, stream>>>(rowptr, col, asrc, adst, hbuf, aggbuf, n);

  // ---------------- h@g + cosine vs mu ----------------
  final_kernel<<<(n + 31) / 32, 256, 0, stream>>>(aggbuf, b2, g, mu, outp, n);
}

// Round 4
// 810.269 us; speedup vs baseline: 2.8776x; 1.1066x over previous
//
#include <hip/hip_runtime.h>
#include <hip/hip_bf16.h>

__device__ __forceinline__ float lrelu(float x, float s) { return x > 0.f ? x : x * s; }

// ---------------- CSR build ----------------
__global__ void deg_init_kernel(int* __restrict__ deg, int n) {
  int i = blockIdx.x * blockDim.x + threadIdx.x;
  if (i < n) deg[i] = 1;   // self-loop
}

__global__ void deg_count_kernel(const int* __restrict__ edst, int* __restrict__ deg, int E) {
  int i = blockIdx.x * blockDim.x + threadIdx.x;
  if (i < E) atomicAdd(&deg[edst[i]], 1);
}

__global__ void __launch_bounds__(256)
scan1_kernel(const int* __restrict__ deg, int* __restrict__ out,
             int* __restrict__ blksum, int n) {
  __shared__ int ts[256];
  const int t = threadIdx.x;
  const int base = blockIdx.x * 2048 + t * 8;
  int v[8]; int s = 0;
  #pragma unroll
  for (int i = 0; i < 8; ++i) {
    int x = (base + i < n) ? deg[base + i] : 0;
    v[i] = s; s += x;
  }
  ts[t] = s;
  __syncthreads();
  for (int off = 1; off < 256; off <<= 1) {
    int add = (t >= off) ? ts[t - off] : 0;
    __syncthreads();
    ts[t] += add;
    __syncthreads();
  }
  const int excl = ts[t] - s;
  #pragma unroll
  for (int i = 0; i < 8; ++i)
    if (base + i < n) out[base + i] = excl + v[i];
  if (t == 255) blksum[blockIdx.x] = ts[255];
}

__global__ void scan2_kernel(int* __restrict__ blksum, int nb) {
  const int t = threadIdx.x;
  int v = (t < nb) ? blksum[t] : 0;
  #pragma unroll
  for (int off = 1; off < 64; off <<= 1) {
    int u = __shfl_up(v, off);
    if (t >= off) v += u;
  }
  if (t < nb) blksum[t] = v;
}

__global__ void scan3_kernel(int* __restrict__ out, const int* __restrict__ blksum, int n) {
  int i = blockIdx.x * blockDim.x + threadIdx.x;
  if (i >= n) return;
  int b = i >> 11;
  if (b > 0) out[i] += blksum[b - 1];
}

__global__ void scatter_kernel(const int* __restrict__ esrc, const int* __restrict__ edst,
                               int* __restrict__ rowptr, int* __restrict__ col,
                               int E, int n) {
  int i = blockIdx.x * blockDim.x + threadIdx.x;
  if (i < E) {
    int s = esrc[i], d = edst[i];
    int p = atomicAdd(&rowptr[d], 1);
    col[p] = s;
  } else if (i < E + n) {
    int d = i - E;
    int p = atomicAdd(&rowptr[d], 1);
    col[p] = d;
  }
}

// ---------------- features + attention dots ----------------
// H (bf16) = act(In (+bias_in, lrelu 0.01)) @ W ; attention dots in f32
template<int HEADS>
__global__ void __launch_bounds__(256)
feat_kernel(const float* __restrict__ In, const float* __restrict__ W,
            const float* __restrict__ att_s, const float* __restrict__ att_d,
            const float* __restrict__ bias_in,
            __hip_bfloat16* __restrict__ Hout, float* __restrict__ a_src, float* __restrict__ a_dst,
            int n)
{
  __shared__ float Wc[32 * 128];
  __shared__ float xs[8][128];
  const int t = threadIdx.x;
  const int nl = t >> 5;
  const int l32 = t & 31;
  const int c0 = l32 * 4;
  const int iters = (n + 7) >> 3;
  for (int it = blockIdx.x; it < iters; it += gridDim.x) {
    const int nbase = it << 3;
    __syncthreads();
    {
      const int r = t >> 5, o = (t & 31) << 2;
      const int node = nbase + r;
      float4 v = make_float4(0.f, 0.f, 0.f, 0.f);
      if (node < n) {
        v = *(const float4*)&In[(size_t)node * 128 + o];
        if (bias_in) {
          const float4 b = *(const float4*)&bias_in[o];
          v.x = lrelu(v.x + b.x, 0.01f); v.y = lrelu(v.y + b.y, 0.01f);
          v.z = lrelu(v.z + b.z, 0.01f); v.w = lrelu(v.w + b.w, 0.01f);
        }
      }
      *(float4*)&xs[r][o] = v;
    }
    float accx = 0.f, accy = 0.f, accz = 0.f, accw = 0.f;
    for (int kc = 0; kc < 4; ++kc) {
      __syncthreads();
      #pragma unroll
      for (int i = 0; i < 4; ++i)
        ((float4*)Wc)[t + i * 256] = ((const float4*)W)[kc * 1024 + t + i * 256];
      __syncthreads();
      #pragma unroll
      for (int kk = 0; kk < 32; ++kk) {
        const float xv = xs[nl][kc * 32 + kk];
        const float4 wv = *(const float4*)&Wc[kk * 128 + c0];
        accx += xv * wv.x; accy += xv * wv.y; accz += xv * wv.z; accw += xv * wv.w;
      }
    }
    const int node = nbase + nl;
    const float4 as = *(const float4*)&att_s[c0];
    const float4 ad = *(const float4*)&att_d[c0];
    float ps = accx * as.x + accy * as.y + accz * as.z + accw * as.w;
    float pd = accx * ad.x + accy * ad.y + accz * ad.z + accw * ad.w;
    const int GROUP = (HEADS == 8) ? 4 : 32;
    #pragma unroll
    for (int off = 1; off < GROUP; off <<= 1) {
      ps += __shfl_xor(ps, off);
      pd += __shfl_xor(pd, off);
    }
    if (node < n) {
      union { __hip_bfloat162 h2[2]; uint2 u; } pk;
      pk.h2[0].x = __float2bfloat16(accx); pk.h2[0].y = __float2bfloat16(accy);
      pk.h2[1].x = __float2bfloat16(accz); pk.h2[1].y = __float2bfloat16(accw);
      *(uint2*)&Hout[(size_t)node * 128 + c0] = pk.u;
      if ((l32 & (GROUP - 1)) == 0) {
        const int h = (HEADS == 8) ? (l32 >> 2) : 0;
        a_src[node * HEADS + h] = ps;
        a_dst[node * HEADS + h] = pd;
      }
    }
  }
}

// ---------------- CSR gather-aggregate (single-pass online softmax, no max shift) ----------------
// one wave per destination node; logits bounded -> exp safe without max subtraction
template<int HEADS>
__global__ void __launch_bounds__(256)
agg_csr_kernel(const int* __restrict__ rowptr_end, const int* __restrict__ col,
               const float* __restrict__ a_src, const float* __restrict__ a_dst,
               const __hip_bfloat16* __restrict__ Hf, float* __restrict__ agg, int n)
{
  const int wave = threadIdx.x >> 6;
  const int lane = threadIdx.x & 63;
  const int d = blockIdx.x * 4 + wave;
  if (d >= n) return;
  const int beg = (d == 0) ? 0 : rowptr_end[d - 1];
  const int end = rowptr_end[d];
  float accx = 0.f, accy = 0.f;

  if (HEADS == 8) {
    const int h  = lane & 7;    // head this lane computes exp for
    const int ei = lane >> 3;   // edge slot 0..7
    const int hf = lane >> 3;   // head of this lane's feature pair (feats 2*lane, 2*lane+1)
    const float adv = a_dst[d * 8 + h];
    float sum = 0.f;
    for (int p0 = beg; p0 < end; p0 += 8) {
      const int cnt = min(8, end - p0);
      int sv = 0; float a = 0.f;
      if (ei < cnt) {
        sv = col[p0 + ei];
        a = __expf(lrelu(a_src[sv * 8 + h] + adv, 0.2f));
        sum += a;
      }
      for (int e = 0; e < cnt; ++e) {
        const float al = __shfl(a, e * 8 + hf);
        const int   s  = __shfl(sv, e * 8);
        const __hip_bfloat162 hv = ((const __hip_bfloat162*)Hf)[(size_t)s * 64 + lane];
        accx += al * __bfloat162float(hv.x);
        accy += al * __bfloat162float(hv.y);
      }
    }
    sum += __shfl_xor(sum, 8);
    sum += __shfl_xor(sum, 16);
    sum += __shfl_xor(sum, 32);
    const float denom = __shfl(sum, hf) + 1e-16f;  // lane hf holds head hf after reduce
    accx /= denom; accy /= denom;
  } else {
    const float adv = a_dst[d];
    float sum = 0.f;
    for (int p0 = beg; p0 < end; p0 += 64) {
      const int cnt = min(64, end - p0);
      int sv = 0; float a = 0.f;
      if (lane < cnt) {
        sv = col[p0 + lane];
        a = __expf(lrelu(a_src[sv] + adv, 0.2f));
        sum += a;
      }
      for (int e = 0; e < cnt; ++e) {
        const float al = __shfl(a, e);
        const int   s  = __shfl(sv, e);
        const __hip_bfloat162 hv = ((const __hip_bfloat162*)Hf)[(size_t)s * 64 + lane];
        accx += al * __bfloat162float(hv.x);
        accy += al * __bfloat162float(hv.y);
      }
    }
    #pragma unroll
    for (int off = 1; off < 64; off <<= 1) sum += __shfl_xor(sum, off);
    const float inv = 1.f / (sum + 1e-16f);
    accx *= inv; accy *= inv;
  }
  *(float2*)&agg[(size_t)d * 128 + lane * 2] = make_float2(accx, accy);
}

// ---------------- h@g + cosine vs mu (register-tiled f32 GEMM) ----------------
__global__ void __launch_bounds__(256, 2)
final_kernel(const float* __restrict__ agg2, const float* __restrict__ b2,
             const float* __restrict__ g, const float* __restrict__ mu,
             float* __restrict__ outp, int n)
{
  __shared__ float os[32][128];
  const int t = threadIdx.x;
  const int wave = t >> 6;
  const int lane = t & 63;
  const int nbase = blockIdx.x << 5;
  #pragma unroll
  for (int i = 0; i < 4; ++i) {
    const int q = t + i * 256;
    const int r = q >> 5, o = (q & 31) << 2;
    const int node = nbase + r;
    float4 v = make_float4(0.f, 0.f, 0.f, 0.f);
    if (node < n) {
      v = *(const float4*)&agg2[(size_t)node * 128 + o];
      const float4 b = *(const float4*)&b2[o];
      v.x += b.x; v.y += b.y; v.z += b.z; v.w += b.w;
    }
    *(float4*)&os[r][o] = v;
  }
  __syncthreads();

  const int r0 = wave * 8;
  const int c0 = lane * 8;
  float acc[8][8];
  #pragma unroll
  for (int r = 0; r < 8; ++r)
    #pragma unroll
    for (int c = 0; c < 8; ++c) acc[r][c] = 0.f;

  for (int k0 = 0; k0 < 128; k0 += 4) {
    float4 ga[4], gb[4];
    #pragma unroll
    for (int kk = 0; kk < 4; ++kk) {
      ga[kk] = *(const float4*)&g[(size_t)(k0 + kk) * 512 + c0];
      gb[kk] = *(const float4*)&g[(size_t)(k0 + kk) * 512 + c0 + 4];
    }
    float4 ov[8];
    #pragma unroll
    for (int r = 0; r < 8; ++r) ov[r] = *(const float4*)&os[r0 + r][k0];
    #pragma unroll
    for (int r = 0; r < 8; ++r) {
      #pragma unroll
      for (int kk = 0; kk < 4; ++kk) {
        const float o = (kk == 0) ? ov[r].x : (kk == 1) ? ov[r].y : (kk == 2) ? ov[r].z : ov[r].w;
        acc[r][0] += o * ga[kk].x;
        acc[r][1] += o * ga[kk].y;
        acc[r][2] += o * ga[kk].z;
        acc[r][3] += o * ga[kk].w;
        acc[r][4] += o * gb[kk].x;
        acc[r][5] += o * gb[kk].y;
        acc[r][6] += o * gb[kk].z;
        acc[r][7] += o * gb[kk].w;
      }
    }
  }

  float mus[8];
  #pragma unroll
  for (int c = 0; c < 8; ++c) mus[c] = mu[c0 + c];
  float munsq = 0.f;
  #pragma unroll
  for (int c = 0; c < 8; ++c) munsq += mus[c] * mus[c];
  munsq += __shfl_xor(munsq, 1);
  munsq += __shfl_xor(munsq, 2);
  munsq += __shfl_xor(munsq, 4);
  const float mun = fmaxf(sqrtf(munsq), 1e-8f);
  const int kgrp = lane >> 3;
  #pragma unroll
  for (int r = 0; r < 8; ++r) {
    float num = 0.f, ss = 0.f;
    #pragma unroll
    for (int c = 0; c < 8; ++c) {
      num += mus[c] * acc[r][c];
      ss  += acc[r][c] * acc[r][c];
    }
    num += __shfl_xor(num, 1); ss += __shfl_xor(ss, 1);
    num += __shfl_xor(num, 2); ss += __shfl_xor(ss, 2);
    num += __shfl_xor(num, 4); ss += __shfl_xor(ss, 4);
    const int node = nbase + r0 + r;
    if ((lane & 7) == 0 && node < n) {
      const float den = mun * fmaxf(sqrtf(ss), 1e-8f);
      outp[(size_t)node * 8 + kgrp] = num / den;
    }
  }
}

extern "C" void kernel_launch(void* const* d_in, const int* in_sizes, int n_in,
                              void* d_out, int out_size, void* d_ws, size_t ws_size,
                              hipStream_t stream)
{
  const float* x   = (const float*)d_in[0];
  const int*   eix = (const int*)d_in[1];
  const float* W1  = (const float*)d_in[2];
  const float* as1 = (const float*)d_in[3];
  const float* ad1 = (const float*)d_in[4];
  const float* b1  = (const float*)d_in[5];
  const float* W2  = (const float*)d_in[6];
  const float* as2 = (const float*)d_in[7];
  const float* ad2 = (const float*)d_in[8];
  const float* b2  = (const float*)d_in[9];
  const float* g   = (const float*)d_in[10];
  const float* mu  = (const float*)d_in[11];
  float* outp = (float*)d_out;

  const int n    = in_sizes[0] / 128;
  const int E    = in_sizes[1] / 2;
  const int Etot = E + n;
  const int* esrc = eix;
  const int* edst = eix + E;

  float* hbuf   = (float*)d_ws;                      // used as bf16 H storage
  float* aggbuf = hbuf   + (size_t)n * 128;
  float* asrc   = aggbuf + (size_t)n * 128;
  float* adst   = asrc   + (size_t)n * 8;
  int*   rowptr = (int*)(adst + (size_t)n * 8);
  int*   col    = rowptr + n;
  int*   deg    = (int*)aggbuf;
  int*   blksum = deg + n;
  __hip_bfloat16* hb = (__hip_bfloat16*)hbuf;

  // ---------------- CSR build (by destination, self-loops included) ----------------
  const int nb = (n + 2047) / 2048;
  deg_init_kernel<<<(n + 255) / 256, 256, 0, stream>>>(deg, n);
  deg_count_kernel<<<(E + 255) / 256, 256, 0, stream>>>(edst, deg, E);
  scan1_kernel<<<nb, 256, 0, stream>>>(deg, rowptr, blksum, n);
  scan2_kernel<<<1, 64, 0, stream>>>(blksum, nb);
  scan3_kernel<<<(n + 255) / 256, 256, 0, stream>>>(rowptr, blksum, n);
  scatter_kernel<<<(Etot + 255) / 256, 256, 0, stream>>>(esrc, edst, rowptr, col, E, n);

  // ---------------- conv1 (heads=8, C=16) ----------------
  feat_kernel<8><<<1024, 256, 0, stream>>>(x, W1, as1, ad1, nullptr, hb, asrc, adst, n);
  agg_csr_kernel<8><<<(n + 3) / 4, 256, 0, stream>>>(rowptr, col, asrc, adst, hb, aggbuf, n);

  // ---------------- conv2 (heads=1, C=128) ----------------
  feat_kernel<1><<<1024, 256, 0, stream>>>(aggbuf, W2, as2, ad2, b1, hb, asrc, adst, n);
  agg_csr_kernel<1><<<(n + 3) / 4, 256, 0, stream>>>(rowptr, col, asrc, adst, hb, aggbuf, n);

  // ---------------- h@g + cosine vs mu ----------------
  final_kernel<<<(n + 31) / 32, 256, 0, stream>>>(aggbuf, b2, g, mu, outp, n);
}

// Round 5
// 711.226 us; speedup vs baseline: 3.2783x; 1.1393x over previous
//
#include <hip/hip_runtime.h>
#include <hip/hip_bf16.h>

typedef short short8 __attribute__((ext_vector_type(8)));
typedef float f32x4 __attribute__((ext_vector_type(4)));

__device__ __forceinline__ float lrelu(float x, float s) { return x > 0.f ? x : x * s; }

__device__ __forceinline__ unsigned short f2bf(float x) {
  union { __hip_bfloat16 b; unsigned short u; } cv;
  cv.b = __float2bfloat16(x);
  return cv.u;
}

// ---------------- CSR build ----------------
__global__ void deg_init_kernel(int* __restrict__ deg, int n) {
  int i = blockIdx.x * blockDim.x + threadIdx.x;
  if (i < n) deg[i] = 1;   // self-loop
}

__global__ void deg_count_kernel(const int* __restrict__ edst, int* __restrict__ deg, int E) {
  int i = blockIdx.x * blockDim.x + threadIdx.x;
  if (i < E) atomicAdd(&deg[edst[i]], 1);
}

__global__ void __launch_bounds__(256)
scan1_kernel(const int* __restrict__ deg, int* __restrict__ out,
             int* __restrict__ blksum, int n) {
  __shared__ int ts[256];
  const int t = threadIdx.x;
  const int base = blockIdx.x * 2048 + t * 8;
  int v[8]; int s = 0;
  #pragma unroll
  for (int i = 0; i < 8; ++i) {
    int x = (base + i < n) ? deg[base + i] : 0;
    v[i] = s; s += x;
  }
  ts[t] = s;
  __syncthreads();
  for (int off = 1; off < 256; off <<= 1) {
    int add = (t >= off) ? ts[t - off] : 0;
    __syncthreads();
    ts[t] += add;
    __syncthreads();
  }
  const int excl = ts[t] - s;
  #pragma unroll
  for (int i = 0; i < 8; ++i)
    if (base + i < n) out[base + i] = excl + v[i];
  if (t == 255) blksum[blockIdx.x] = ts[255];
}

__global__ void scan2_kernel(int* __restrict__ blksum, int nb) {
  const int t = threadIdx.x;
  int v = (t < nb) ? blksum[t] : 0;
  #pragma unroll
  for (int off = 1; off < 64; off <<= 1) {
    int u = __shfl_up(v, off);
    if (t >= off) v += u;
  }
  if (t < nb) blksum[t] = v;
}

__global__ void scan3_kernel(int* __restrict__ out, const int* __restrict__ blksum, int n) {
  int i = blockIdx.x * blockDim.x + threadIdx.x;
  if (i >= n) return;
  int b = i >> 11;
  if (b > 0) out[i] += blksum[b - 1];
}

__global__ void scatter_kernel(const int* __restrict__ esrc, const int* __restrict__ edst,
                               int* __restrict__ rowptr, int* __restrict__ col,
                               int E, int n) {
  int i = blockIdx.x * blockDim.x + threadIdx.x;
  if (i < E) {
    int s = esrc[i], d = edst[i];
    int p = atomicAdd(&rowptr[d], 1);
    col[p] = s;
  } else if (i < E + n) {
    int d = i - E;
    int p = atomicAdd(&rowptr[d], 1);
    col[p] = d;
  }
}

// ---------------- g -> gt (bf16, transposed [512][128]) ----------------
__global__ void __launch_bounds__(256)
gprep_kernel(const float* __restrict__ g, unsigned short* __restrict__ gt) {
  __shared__ float ts[32][68];
  const int t = threadIdx.x;
  const int kb = (blockIdx.x >> 3) * 32;   // k block 0..3
  const int cb = (blockIdx.x & 7) * 64;    // c block 0..7
  {
    const int r = t >> 3;            // 0..31
    const int c = (t & 7) * 8;       // 0..56
    float4 v0 = *(const float4*)&g[(size_t)(kb + r) * 512 + cb + c];
    float4 v1 = *(const float4*)&g[(size_t)(kb + r) * 512 + cb + c + 4];
    *(float4*)&ts[r][c] = v0;
    *(float4*)&ts[r][c + 4] = v1;
  }
  __syncthreads();
  {
    const int c = t >> 2;            // 0..63
    const int k0 = (t & 3) * 8;      // 0,8,16,24
    unsigned short pk[8];
    #pragma unroll
    for (int j = 0; j < 8; ++j) pk[j] = f2bf(ts[k0 + j][c]);
    *(short8*)&gt[(size_t)(cb + c) * 128 + kb + k0] = *(short8*)pk;
  }
}

// ---------------- features + attention dots ----------------
// H (bf16) = act(In (+bias_in, lrelu 0.01)) @ W ; attention dots in f32
template<int HEADS>
__global__ void __launch_bounds__(256)
feat_kernel(const float* __restrict__ In, const float* __restrict__ W,
            const float* __restrict__ att_s, const float* __restrict__ att_d,
            const float* __restrict__ bias_in,
            __hip_bfloat16* __restrict__ Hout, float* __restrict__ a_src, float* __restrict__ a_dst,
            int n)
{
  __shared__ float Wc[32 * 128];
  __shared__ float xs[8][128];
  const int t = threadIdx.x;
  const int nl = t >> 5;
  const int l32 = t & 31;
  const int c0 = l32 * 4;
  const int iters = (n + 7) >> 3;
  for (int it = blockIdx.x; it < iters; it += gridDim.x) {
    const int nbase = it << 3;
    __syncthreads();
    {
      const int r = t >> 5, o = (t & 31) << 2;
      const int node = nbase + r;
      float4 v = make_float4(0.f, 0.f, 0.f, 0.f);
      if (node < n) {
        v = *(const float4*)&In[(size_t)node * 128 + o];
        if (bias_in) {
          const float4 b = *(const float4*)&bias_in[o];
          v.x = lrelu(v.x + b.x, 0.01f); v.y = lrelu(v.y + b.y, 0.01f);
          v.z = lrelu(v.z + b.z, 0.01f); v.w = lrelu(v.w + b.w, 0.01f);
        }
      }
      *(float4*)&xs[r][o] = v;
    }
    float accx = 0.f, accy = 0.f, accz = 0.f, accw = 0.f;
    for (int kc = 0; kc < 4; ++kc) {
      __syncthreads();
      #pragma unroll
      for (int i = 0; i < 4; ++i)
        ((float4*)Wc)[t + i * 256] = ((const float4*)W)[kc * 1024 + t + i * 256];
      __syncthreads();
      #pragma unroll
      for (int kk = 0; kk < 32; ++kk) {
        const float xv = xs[nl][kc * 32 + kk];
        const float4 wv = *(const float4*)&Wc[kk * 128 + c0];
        accx += xv * wv.x; accy += xv * wv.y; accz += xv * wv.z; accw += xv * wv.w;
      }
    }
    const int node = nbase + nl;
    const float4 as = *(const float4*)&att_s[c0];
    const float4 ad = *(const float4*)&att_d[c0];
    float ps = accx * as.x + accy * as.y + accz * as.z + accw * as.w;
    float pd = accx * ad.x + accy * ad.y + accz * ad.z + accw * ad.w;
    const int GROUP = (HEADS == 8) ? 4 : 32;
    #pragma unroll
    for (int off = 1; off < GROUP; off <<= 1) {
      ps += __shfl_xor(ps, off);
      pd += __shfl_xor(pd, off);
    }
    if (node < n) {
      unsigned short pk[4];
      pk[0] = f2bf(accx); pk[1] = f2bf(accy); pk[2] = f2bf(accz); pk[3] = f2bf(accw);
      *(uint2*)&Hout[(size_t)node * 128 + c0] = *(uint2*)pk;
      if ((l32 & (GROUP - 1)) == 0) {
        const int h = (HEADS == 8) ? (l32 >> 2) : 0;
        a_src[node * HEADS + h] = ps;
        a_dst[node * HEADS + h] = pd;
      }
    }
  }
}

// ---------------- CSR gather-aggregate (single-pass online softmax, no max shift) ----------------
template<int HEADS>
__global__ void __launch_bounds__(256)
agg_csr_kernel(const int* __restrict__ rowptr_end, const int* __restrict__ col,
               const float* __restrict__ a_src, const float* __restrict__ a_dst,
               const __hip_bfloat16* __restrict__ Hf, float* __restrict__ agg, int n)
{
  const int wave = threadIdx.x >> 6;
  const int lane = threadIdx.x & 63;
  const int d = blockIdx.x * 4 + wave;
  if (d >= n) return;
  const int beg = (d == 0) ? 0 : rowptr_end[d - 1];
  const int end = rowptr_end[d];
  float accx = 0.f, accy = 0.f;

  if (HEADS == 8) {
    const int h  = lane & 7;
    const int ei = lane >> 3;
    const int hf = lane >> 3;
    const float adv = a_dst[d * 8 + h];
    float sum = 0.f;
    for (int p0 = beg; p0 < end; p0 += 8) {
      const int cnt = min(8, end - p0);
      int sv = 0; float a = 0.f;
      if (ei < cnt) {
        sv = col[p0 + ei];
        a = __expf(lrelu(a_src[sv * 8 + h] + adv, 0.2f));
        sum += a;
      }
      for (int e = 0; e < cnt; ++e) {
        const float al = __shfl(a, e * 8 + hf);
        const int   s  = __shfl(sv, e * 8);
        const __hip_bfloat162 hv = ((const __hip_bfloat162*)Hf)[(size_t)s * 64 + lane];
        accx += al * __bfloat162float(hv.x);
        accy += al * __bfloat162float(hv.y);
      }
    }
    sum += __shfl_xor(sum, 8);
    sum += __shfl_xor(sum, 16);
    sum += __shfl_xor(sum, 32);
    const float denom = __shfl(sum, hf) + 1e-16f;
    accx /= denom; accy /= denom;
  } else {
    const float adv = a_dst[d];
    float sum = 0.f;
    for (int p0 = beg; p0 < end; p0 += 64) {
      const int cnt = min(64, end - p0);
      int sv = 0; float a = 0.f;
      if (lane < cnt) {
        sv = col[p0 + lane];
        a = __expf(lrelu(a_src[sv] + adv, 0.2f));
        sum += a;
      }
      for (int e = 0; e < cnt; ++e) {
        const float al = __shfl(a, e);
        const int   s  = __shfl(sv, e);
        const __hip_bfloat162 hv = ((const __hip_bfloat162*)Hf)[(size_t)s * 64 + lane];
        accx += al * __bfloat162float(hv.x);
        accy += al * __bfloat162float(hv.y);
      }
    }
    #pragma unroll
    for (int off = 1; off < 64; off <<= 1) sum += __shfl_xor(sum, off);
    const float inv = 1.f / (sum + 1e-16f);
    accx *= inv; accy *= inv;
  }
  *(float2*)&agg[(size_t)d * 128 + lane * 2] = make_float2(accx, accy);
}

// ---------------- h@g + cosine vs mu (bf16 MFMA GEMM) ----------------
// block = 256 threads / 4 waves; tile = 32 nodes x 512 cols; wave w -> cols [w*128, w*128+128)
// MFMA 16x16x32: A lane layout row=l&15, k=(l>>4)*8+j ; B col=l&15, k=(l>>4)*8+j ;
// C/D col=l&15, row=(l>>4)*4+reg  [m89-verified]
__global__ void __launch_bounds__(256)
final_kernel(const float* __restrict__ agg2, const float* __restrict__ b2,
             const unsigned short* __restrict__ gt, const float* __restrict__ mu,
             float* __restrict__ outp, int n)
{
  __shared__ unsigned short os[32][136];   // 32 nodes x 128 k, pad to 136 (272B rows, 16B-aligned)
  const int t = threadIdx.x;
  const int w = t >> 6;
  const int lane = t & 63;
  const int l15 = lane & 15;
  const int lg = lane >> 4;
  const int nbase = blockIdx.x << 5;

  // stage A: (agg2 + b2) -> bf16 LDS
  {
    const int r = t >> 3;            // 0..31
    const int c = (t & 7) * 16;      // 0..112
    const int node = nbase + r;
    unsigned short pk[16];
    if (node < n) {
      #pragma unroll
      for (int i = 0; i < 4; ++i) {
        float4 v = *(const float4*)&agg2[(size_t)node * 128 + c + i * 4];
        const float4 b = *(const float4*)&b2[c + i * 4];
        pk[i * 4 + 0] = f2bf(v.x + b.x);
        pk[i * 4 + 1] = f2bf(v.y + b.y);
        pk[i * 4 + 2] = f2bf(v.z + b.z);
        pk[i * 4 + 3] = f2bf(v.w + b.w);
      }
    } else {
      #pragma unroll
      for (int i = 0; i < 16; ++i) pk[i] = 0;
    }
    *(short8*)&os[r][c]     = *(short8*)&pk[0];
    *(short8*)&os[r][c + 8] = *(short8*)&pk[8];
  }
  __syncthreads();

  // A fragments: 2 row-tiles x 4 k-chunks
  short8 afr[2][4];
  #pragma unroll
  for (int rt = 0; rt < 2; ++rt)
    #pragma unroll
    for (int kc = 0; kc < 4; ++kc)
      afr[rt][kc] = *(const short8*)&os[rt * 16 + l15][kc * 32 + lg * 8];

  // B base: gt[col][k], col = w*128 + ct*16 + l15, k = kc*32 + lg*8
  const unsigned short* gw = gt + (size_t)(w * 128 + l15) * 128 + lg * 8;

  f32x4 acc[2][8];
  #pragma unroll
  for (int rt = 0; rt < 2; ++rt)
    #pragma unroll
    for (int ct = 0; ct < 8; ++ct)
      acc[rt][ct] = (f32x4){0.f, 0.f, 0.f, 0.f};

  short8 bcur[8], bnxt[8];
  #pragma unroll
  for (int ct = 0; ct < 8; ++ct)
    bcur[ct] = *(const short8*)&gw[(size_t)ct * 2048];

  #pragma unroll
  for (int kc = 0; kc < 4; ++kc) {
    if (kc < 3) {
      #pragma unroll
      for (int ct = 0; ct < 8; ++ct)
        bnxt[ct] = *(const short8*)&gw[(size_t)ct * 2048 + (kc + 1) * 32];
    }
    #pragma unroll
    for (int ct = 0; ct < 8; ++ct) {
      acc[0][ct] = __builtin_amdgcn_mfma_f32_16x16x32_bf16(afr[0][kc], bcur[ct], acc[0][ct], 0, 0, 0);
      acc[1][ct] = __builtin_amdgcn_mfma_f32_16x16x32_bf16(afr[1][kc], bcur[ct], acc[1][ct], 0, 0, 0);
    }
    if (kc < 3) {
      #pragma unroll
      for (int ct = 0; ct < 8; ++ct) bcur[ct] = bnxt[ct];
    }
  }

  // epilogue: cosine vs mu; k-group kg covers 64 cols = 4 C-tiles
  #pragma unroll
  for (int kg = 0; kg < 2; ++kg) {
    const int k = w * 2 + kg;
    float muv[4];
    #pragma unroll
    for (int ct = 0; ct < 4; ++ct) muv[ct] = mu[k * 64 + ct * 16 + l15];
    float mq = 0.f;
    #pragma unroll
    for (int ct = 0; ct < 4; ++ct) mq += muv[ct] * muv[ct];
    mq += __shfl_xor(mq, 1); mq += __shfl_xor(mq, 2);
    mq += __shfl_xor(mq, 4); mq += __shfl_xor(mq, 8);
    const float mun = fmaxf(sqrtf(mq), 1e-8f);
    #pragma unroll
    for (int rt = 0; rt < 2; ++rt) {
      float num[4] = {0.f, 0.f, 0.f, 0.f};
      float ss[4]  = {0.f, 0.f, 0.f, 0.f};
      #pragma unroll
      for (int ct = 0; ct < 4; ++ct) {
        const f32x4 a = acc[rt][kg * 4 + ct];
        #pragma unroll
        for (int r = 0; r < 4; ++r) {
          num[r] += muv[ct] * a[r];
          ss[r]  += a[r] * a[r];
        }
      }
      #pragma unroll
      for (int r = 0; r < 4; ++r) {
        num[r] += __shfl_xor(num[r], 1); ss[r] += __shfl_xor(ss[r], 1);
        num[r] += __shfl_xor(num[r], 2); ss[r] += __shfl_xor(ss[r], 2);
        num[r] += __shfl_xor(num[r], 4); ss[r] += __shfl_xor(ss[r], 4);
        num[r] += __shfl_xor(num[r], 8); ss[r] += __shfl_xor(ss[r], 8);
      }
      if (l15 == 0) {
        #pragma unroll
        for (int r = 0; r < 4; ++r) {
          const int node = nbase + rt * 16 + lg * 4 + r;
          if (node < n) {
            const float den = mun * fmaxf(sqrtf(ss[r]), 1e-8f);
            outp[(size_t)node * 8 + k] = num[r] / den;
          }
        }
      }
    }
  }
}

extern "C" void kernel_launch(void* const* d_in, const int* in_sizes, int n_in,
                              void* d_out, int out_size, void* d_ws, size_t ws_size,
                              hipStream_t stream)
{
  const float* x   = (const float*)d_in[0];
  const int*   eix = (const int*)d_in[1];
  const float* W1  = (const float*)d_in[2];
  const float* as1 = (const float*)d_in[3];
  const float* ad1 = (const float*)d_in[4];
  const float* b1  = (const float*)d_in[5];
  const float* W2  = (const float*)d_in[6];
  const float* as2 = (const float*)d_in[7];
  const float* ad2 = (const float*)d_in[8];
  const float* b2  = (const float*)d_in[9];
  const float* g   = (const float*)d_in[10];
  const float* mu  = (const float*)d_in[11];
  float* outp = (float*)d_out;

  const int n    = in_sizes[0] / 128;
  const int E    = in_sizes[1] / 2;
  const int Etot = E + n;
  const int* esrc = eix;
  const int* edst = eix + E;

  float* hbuf   = (float*)d_ws;                      // holds bf16 H (first n*128 bf16); gt in upper half
  float* aggbuf = hbuf   + (size_t)n * 128;
  float* asrc   = aggbuf + (size_t)n * 128;
  float* adst   = asrc   + (size_t)n * 8;
  int*   rowptr = (int*)(adst + (size_t)n * 8);
  int*   col    = rowptr + n;
  int*   deg    = (int*)aggbuf;
  int*   blksum = deg + n;
  __hip_bfloat16* hb = (__hip_bfloat16*)hbuf;
  unsigned short* gt = (unsigned short*)hbuf + (size_t)n * 128;  // 512x128 bf16 in unused half of hbuf region

  // ---------------- g -> gt (bf16 transposed) ----------------
  gprep_kernel<<<32, 256, 0, stream>>>(g, gt);

  // ---------------- CSR build (by destination, self-loops included) ----------------
  const int nb = (n + 2047) / 2048;
  deg_init_kernel<<<(n + 255) / 256, 256, 0, stream>>>(deg, n);
  deg_count_kernel<<<(E + 255) / 256, 256, 0, stream>>>(edst, deg, E);
  scan1_kernel<<<nb, 256, 0, stream>>>(deg, rowptr, blksum, n);
  scan2_kernel<<<1, 64, 0, stream>>>(blksum, nb);
  scan3_kernel<<<(n + 255) / 256, 256, 0, stream>>>(rowptr, blksum, n);
  scatter_kernel<<<(Etot + 255) / 256, 256, 0, stream>>>(esrc, edst, rowptr, col, E, n);

  // ---------------- conv1 (heads=8, C=16) ----------------
  feat_kernel<8><<<1024, 256, 0, stream>>>(x, W1, as1, ad1, nullptr, hb, asrc, adst, n);
  agg_csr_kernel<8><<<(n + 3) / 4, 256, 0, stream>>>(rowptr, col, asrc, adst, hb, aggbuf, n);

  // ---------------- conv2 (heads=1, C=128) ----------------
  feat_kernel<1><<<1024, 256, 0, stream>>>(aggbuf, W2, as2, ad2, b1, hb, asrc, adst, n);
  agg_csr_kernel<1><<<(n + 3) / 4, 256, 0, stream>>>(rowptr, col, asrc, adst, hb, aggbuf, n);

  // ---------------- h@g + cosine vs mu ----------------
  final_kernel<<<(n + 31) / 32, 256, 0, stream>>>(aggbuf, b2, gt, mu, outp, n);
}

// Round 6
// 666.723 us; speedup vs baseline: 3.4972x; 1.0667x over previous
//
#include <hip/hip_runtime.h>
#include <hip/hip_bf16.h>

typedef short short8 __attribute__((ext_vector_type(8)));
typedef float f32x4 __attribute__((ext_vector_type(4)));

__device__ __forceinline__ float lrelu(float x, float s) { return x > 0.f ? x : x * s; }

__device__ __forceinline__ unsigned short f2bf(float x) {
  union { __hip_bfloat16 b; unsigned short u; } cv;
  cv.b = __float2bfloat16(x);
  return cv.u;
}

// ---------------- CSR build ----------------
__global__ void deg_init_kernel(int* __restrict__ deg, int n) {
  int i = blockIdx.x * blockDim.x + threadIdx.x;
  if (i < n) deg[i] = 1;   // self-loop
}

// XCD-local counting: group g = bid&3 handles dst in [lo,hi); blocks of group g
// land on XCDs {g, g+4} (round-robin bid%8), so deg lines stay in 2 L2s.
__global__ void __launch_bounds__(256)
deg_count_kernel(const int* __restrict__ edst, int* __restrict__ deg, int E, int n) {
  const int grp = blockIdx.x & 3;
  const int lo = (int)(((long long)n * grp) >> 2);
  const int hi = (int)(((long long)n * (grp + 1)) >> 2);
  const int tid = (blockIdx.x >> 2) * blockDim.x + threadIdx.x;
  const int stride = (gridDim.x >> 2) * blockDim.x;
  for (int i = tid; i < E; i += stride) {
    const int d = edst[i];
    if (d >= lo && d < hi) atomicAdd(&deg[d], 1);
  }
}

__global__ void __launch_bounds__(256)
scan1_kernel(const int* __restrict__ deg, int* __restrict__ out,
             int* __restrict__ blksum, int n) {
  __shared__ int ts[256];
  const int t = threadIdx.x;
  const int base = blockIdx.x * 2048 + t * 8;
  int v[8]; int s = 0;
  #pragma unroll
  for (int i = 0; i < 8; ++i) {
    int x = (base + i < n) ? deg[base + i] : 0;
    v[i] = s; s += x;
  }
  ts[t] = s;
  __syncthreads();
  for (int off = 1; off < 256; off <<= 1) {
    int add = (t >= off) ? ts[t - off] : 0;
    __syncthreads();
    ts[t] += add;
    __syncthreads();
  }
  const int excl = ts[t] - s;
  #pragma unroll
  for (int i = 0; i < 8; ++i)
    if (base + i < n) out[base + i] = excl + v[i];
  if (t == 255) blksum[blockIdx.x] = ts[255];
}

__global__ void scan2_kernel(int* __restrict__ blksum, int nb) {
  const int t = threadIdx.x;
  int v = (t < nb) ? blksum[t] : 0;
  #pragma unroll
  for (int off = 1; off < 64; off <<= 1) {
    int u = __shfl_up(v, off);
    if (t >= off) v += u;
  }
  if (t < nb) blksum[t] = v;
}

__global__ void scan3_kernel(int* __restrict__ out, const int* __restrict__ blksum, int n) {
  int i = blockIdx.x * blockDim.x + threadIdx.x;
  if (i >= n) return;
  int b = i >> 11;
  if (b > 0) out[i] += blksum[b - 1];
}

// XCD-local scatter: same grouping as deg_count. col window per group ~1.7MB,
// touched by 2 XCDs only -> lines accumulate writes in L2 instead of bouncing.
__global__ void __launch_bounds__(256)
scatter_kernel(const int* __restrict__ esrc, const int* __restrict__ edst,
               int* __restrict__ rowptr, int* __restrict__ col,
               int E, int n) {
  const int grp = blockIdx.x & 3;
  const int lo = (int)(((long long)n * grp) >> 2);
  const int hi = (int)(((long long)n * (grp + 1)) >> 2);
  const int tid = (blockIdx.x >> 2) * blockDim.x + threadIdx.x;
  const int stride = (gridDim.x >> 2) * blockDim.x;
  const int Etot = E + n;
  for (int i = tid; i < Etot; i += stride) {
    int s, d;
    if (i < E) { s = esrc[i]; d = edst[i]; } else { s = d = i - E; }
    if (d >= lo && d < hi) {
      int p = atomicAdd(&rowptr[d], 1);
      col[p] = s;
    }
  }
}

// ---------------- g -> gt (bf16, transposed [512][128]) ----------------
__global__ void __launch_bounds__(256)
gprep_kernel(const float* __restrict__ g, unsigned short* __restrict__ gt) {
  __shared__ float ts[32][68];
  const int t = threadIdx.x;
  const int kb = (blockIdx.x >> 3) * 32;   // k block 0..3
  const int cb = (blockIdx.x & 7) * 64;    // c block 0..7
  {
    const int r = t >> 3;            // 0..31
    const int c = (t & 7) * 8;       // 0..56
    float4 v0 = *(const float4*)&g[(size_t)(kb + r) * 512 + cb + c];
    float4 v1 = *(const float4*)&g[(size_t)(kb + r) * 512 + cb + c + 4];
    *(float4*)&ts[r][c] = v0;
    *(float4*)&ts[r][c + 4] = v1;
  }
  __syncthreads();
  {
    const int c = t >> 2;            // 0..63
    const int k0 = (t & 3) * 8;      // 0,8,16,24
    unsigned short pk[8];
    #pragma unroll
    for (int j = 0; j < 8; ++j) pk[j] = f2bf(ts[k0 + j][c]);
    *(short8*)&gt[(size_t)(cb + c) * 128 + kb + k0] = *(short8*)pk;
  }
}

// ---------------- features + attention dots ----------------
// H (bf16) = act(In (+bias_in, lrelu 0.01)) @ W ; attention dots in f32
template<int HEADS>
__global__ void __launch_bounds__(256)
feat_kernel(const float* __restrict__ In, const float* __restrict__ W,
            const float* __restrict__ att_s, const float* __restrict__ att_d,
            const float* __restrict__ bias_in,
            __hip_bfloat16* __restrict__ Hout, float* __restrict__ a_src, float* __restrict__ a_dst,
            int n)
{
  __shared__ float Wc[32 * 128];
  __shared__ float xs[8][128];
  const int t = threadIdx.x;
  const int nl = t >> 5;
  const int l32 = t & 31;
  const int c0 = l32 * 4;
  const int iters = (n + 7) >> 3;
  for (int it = blockIdx.x; it < iters; it += gridDim.x) {
    const int nbase = it << 3;
    __syncthreads();
    {
      const int r = t >> 5, o = (t & 31) << 2;
      const int node = nbase + r;
      float4 v = make_float4(0.f, 0.f, 0.f, 0.f);
      if (node < n) {
        v = *(const float4*)&In[(size_t)node * 128 + o];
        if (bias_in) {
          const float4 b = *(const float4*)&bias_in[o];
          v.x = lrelu(v.x + b.x, 0.01f); v.y = lrelu(v.y + b.y, 0.01f);
          v.z = lrelu(v.z + b.z, 0.01f); v.w = lrelu(v.w + b.w, 0.01f);
        }
      }
      *(float4*)&xs[r][o] = v;
    }
    float accx = 0.f, accy = 0.f, accz = 0.f, accw = 0.f;
    for (int kc = 0; kc < 4; ++kc) {
      __syncthreads();
      #pragma unroll
      for (int i = 0; i < 4; ++i)
        ((float4*)Wc)[t + i * 256] = ((const float4*)W)[kc * 1024 + t + i * 256];
      __syncthreads();
      #pragma unroll
      for (int kk = 0; kk < 32; ++kk) {
        const float xv = xs[nl][kc * 32 + kk];
        const float4 wv = *(const float4*)&Wc[kk * 128 + c0];
        accx += xv * wv.x; accy += xv * wv.y; accz += xv * wv.z; accw += xv * wv.w;
      }
    }
    const int node = nbase + nl;
    const float4 as = *(const float4*)&att_s[c0];
    const float4 ad = *(const float4*)&att_d[c0];
    float ps = accx * as.x + accy * as.y + accz * as.z + accw * as.w;
    float pd = accx * ad.x + accy * ad.y + accz * ad.z + accw * ad.w;
    const int GROUP = (HEADS == 8) ? 4 : 32;
    #pragma unroll
    for (int off = 1; off < GROUP; off <<= 1) {
      ps += __shfl_xor(ps, off);
      pd += __shfl_xor(pd, off);
    }
    if (node < n) {
      unsigned short pk[4];
      pk[0] = f2bf(accx); pk[1] = f2bf(accy); pk[2] = f2bf(accz); pk[3] = f2bf(accw);
      *(uint2*)&Hout[(size_t)node * 128 + c0] = *(uint2*)pk;
      if ((l32 & (GROUP - 1)) == 0) {
        const int h = (HEADS == 8) ? (l32 >> 2) : 0;
        a_src[node * HEADS + h] = ps;
        a_dst[node * HEADS + h] = pd;
      }
    }
  }
}

// ---------------- CSR gather-aggregate (single-pass online softmax, no max shift) ----------------
template<int HEADS>
__global__ void __launch_bounds__(256)
agg_csr_kernel(const int* __restrict__ rowptr_end, const int* __restrict__ col,
               const float* __restrict__ a_src, const float* __restrict__ a_dst,
               const __hip_bfloat16* __restrict__ Hf, float* __restrict__ agg, int n)
{
  const int wave = threadIdx.x >> 6;
  const int lane = threadIdx.x & 63;
  const int d = blockIdx.x * 4 + wave;
  if (d >= n) return;
  const int beg = (d == 0) ? 0 : rowptr_end[d - 1];
  const int end = rowptr_end[d];
  float accx = 0.f, accy = 0.f;

  if (HEADS == 8) {
    const int h  = lane & 7;
    const int ei = lane >> 3;
    const int hf = lane >> 3;
    const float adv = a_dst[d * 8 + h];
    float sum = 0.f;
    for (int p0 = beg; p0 < end; p0 += 8) {
      const int cnt = min(8, end - p0);
      int sv = 0; float a = 0.f;
      if (ei < cnt) {
        sv = col[p0 + ei];
        a = __expf(lrelu(a_src[sv * 8 + h] + adv, 0.2f));
        sum += a;
      }
      for (int e = 0; e < cnt; ++e) {
        const float al = __shfl(a, e * 8 + hf);
        const int   s  = __shfl(sv, e * 8);
        const __hip_bfloat162 hv = ((const __hip_bfloat162*)Hf)[(size_t)s * 64 + lane];
        accx += al * __bfloat162float(hv.x);
        accy += al * __bfloat162float(hv.y);
      }
    }
    sum += __shfl_xor(sum, 8);
    sum += __shfl_xor(sum, 16);
    sum += __shfl_xor(sum, 32);
    const float denom = __shfl(sum, hf) + 1e-16f;
    accx /= denom; accy /= denom;
  } else {
    const float adv = a_dst[d];
    float sum = 0.f;
    for (int p0 = beg; p0 < end; p0 += 64) {
      const int cnt = min(64, end - p0);
      int sv = 0; float a = 0.f;
      if (lane < cnt) {
        sv = col[p0 + lane];
        a = __expf(lrelu(a_src[sv] + adv, 0.2f));
        sum += a;
      }
      for (int e = 0; e < cnt; ++e) {
        const float al = __shfl(a, e);
        const int   s  = __shfl(sv, e);
        const __hip_bfloat162 hv = ((const __hip_bfloat162*)Hf)[(size_t)s * 64 + lane];
        accx += al * __bfloat162float(hv.x);
        accy += al * __bfloat162float(hv.y);
      }
    }
    #pragma unroll
    for (int off = 1; off < 64; off <<= 1) sum += __shfl_xor(sum, off);
    const float inv = 1.f / (sum + 1e-16f);
    accx *= inv; accy *= inv;
  }
  *(float2*)&agg[(size_t)d * 128 + lane * 2] = make_float2(accx, accy);
}

// ---------------- h@g + cosine vs mu (bf16 MFMA GEMM) ----------------
__global__ void __launch_bounds__(256)
final_kernel(const float* __restrict__ agg2, const float* __restrict__ b2,
             const unsigned short* __restrict__ gt, const float* __restrict__ mu,
             float* __restrict__ outp, int n)
{
  __shared__ unsigned short os[32][136];
  const int t = threadIdx.x;
  const int w = t >> 6;
  const int lane = t & 63;
  const int l15 = lane & 15;
  const int lg = lane >> 4;
  const int nbase = blockIdx.x << 5;

  {
    const int r = t >> 3;
    const int c = (t & 7) * 16;
    const int node = nbase + r;
    unsigned short pk[16];
    if (node < n) {
      #pragma unroll
      for (int i = 0; i < 4; ++i) {
        float4 v = *(const float4*)&agg2[(size_t)node * 128 + c + i * 4];
        const float4 b = *(const float4*)&b2[c + i * 4];
        pk[i * 4 + 0] = f2bf(v.x + b.x);
        pk[i * 4 + 1] = f2bf(v.y + b.y);
        pk[i * 4 + 2] = f2bf(v.z + b.z);
        pk[i * 4 + 3] = f2bf(v.w + b.w);
      }
    } else {
      #pragma unroll
      for (int i = 0; i < 16; ++i) pk[i] = 0;
    }
    *(short8*)&os[r][c]     = *(short8*)&pk[0];
    *(short8*)&os[r][c + 8] = *(short8*)&pk[8];
  }
  __syncthreads();

  short8 afr[2][4];
  #pragma unroll
  for (int rt = 0; rt < 2; ++rt)
    #pragma unroll
    for (int kc = 0; kc < 4; ++kc)
      afr[rt][kc] = *(const short8*)&os[rt * 16 + l15][kc * 32 + lg * 8];

  const unsigned short* gw = gt + (size_t)(w * 128 + l15) * 128 + lg * 8;

  f32x4 acc[2][8];
  #pragma unroll
  for (int rt = 0; rt < 2; ++rt)
    #pragma unroll
    for (int ct = 0; ct < 8; ++ct)
      acc[rt][ct] = (f32x4){0.f, 0.f, 0.f, 0.f};

  short8 bcur[8], bnxt[8];
  #pragma unroll
  for (int ct = 0; ct < 8; ++ct)
    bcur[ct] = *(const short8*)&gw[(size_t)ct * 2048];

  #pragma unroll
  for (int kc = 0; kc < 4; ++kc) {
    if (kc < 3) {
      #pragma unroll
      for (int ct = 0; ct < 8; ++ct)
        bnxt[ct] = *(const short8*)&gw[(size_t)ct * 2048 + (kc + 1) * 32];
    }
    #pragma unroll
    for (int ct = 0; ct < 8; ++ct) {
      acc[0][ct] = __builtin_amdgcn_mfma_f32_16x16x32_bf16(afr[0][kc], bcur[ct], acc[0][ct], 0, 0, 0);
      acc[1][ct] = __builtin_amdgcn_mfma_f32_16x16x32_bf16(afr[1][kc], bcur[ct], acc[1][ct], 0, 0, 0);
    }
    if (kc < 3) {
      #pragma unroll
      for (int ct = 0; ct < 8; ++ct) bcur[ct] = bnxt[ct];
    }
  }

  #pragma unroll
  for (int kg = 0; kg < 2; ++kg) {
    const int k = w * 2 + kg;
    float muv[4];
    #pragma unroll
    for (int ct = 0; ct < 4; ++ct) muv[ct] = mu[k * 64 + ct * 16 + l15];
    float mq = 0.f;
    #pragma unroll
    for (int ct = 0; ct < 4; ++ct) mq += muv[ct] * muv[ct];
    mq += __shfl_xor(mq, 1); mq += __shfl_xor(mq, 2);
    mq += __shfl_xor(mq, 4); mq += __shfl_xor(mq, 8);
    const float mun = fmaxf(sqrtf(mq), 1e-8f);
    #pragma unroll
    for (int rt = 0; rt < 2; ++rt) {
      float num[4] = {0.f, 0.f, 0.f, 0.f};
      float ss[4]  = {0.f, 0.f, 0.f, 0.f};
      #pragma unroll
      for (int ct = 0; ct < 4; ++ct) {
        const f32x4 a = acc[rt][kg * 4 + ct];
        #pragma unroll
        for (int r = 0; r < 4; ++r) {
          num[r] += muv[ct] * a[r];
          ss[r]  += a[r] * a[r];
        }
      }
      #pragma unroll
      for (int r = 0; r < 4; ++r) {
        num[r] += __shfl_xor(num[r], 1); ss[r] += __shfl_xor(ss[r], 1);
        num[r] += __shfl_xor(num[r], 2); ss[r] += __shfl_xor(ss[r], 2);
        num[r] += __shfl_xor(num[r], 4); ss[r] += __shfl_xor(ss[r], 4);
        num[r] += __shfl_xor(num[r], 8); ss[r] += __shfl_xor(ss[r], 8);
      }
      if (l15 == 0) {
        #pragma unroll
        for (int r = 0; r < 4; ++r) {
          const int node = nbase + rt * 16 + lg * 4 + r;
          if (node < n) {
            const float den = mun * fmaxf(sqrtf(ss[r]), 1e-8f);
            outp[(size_t)node * 8 + k] = num[r] / den;
          }
        }
      }
    }
  }
}

extern "C" void kernel_launch(void* const* d_in, const int* in_sizes, int n_in,
                              void* d_out, int out_size, void* d_ws, size_t ws_size,
                              hipStream_t stream)
{
  const float* x   = (const float*)d_in[0];
  const int*   eix = (const int*)d_in[1];
  const float* W1  = (const float*)d_in[2];
  const float* as1 = (const float*)d_in[3];
  const float* ad1 = (const float*)d_in[4];
  const float* b1  = (const float*)d_in[5];
  const float* W2  = (const float*)d_in[6];
  const float* as2 = (const float*)d_in[7];
  const float* ad2 = (const float*)d_in[8];
  const float* b2  = (const float*)d_in[9];
  const float* g   = (const float*)d_in[10];
  const float* mu  = (const float*)d_in[11];
  float* outp = (float*)d_out;

  const int n    = in_sizes[0] / 128;
  const int E    = in_sizes[1] / 2;
  const int Etot = E + n;
  const int* esrc = eix;
  const int* edst = eix + E;

  float* hbuf   = (float*)d_ws;                      // bf16 H in lower half; gt in upper half
  float* aggbuf = hbuf   + (size_t)n * 128;
  float* asrc   = aggbuf + (size_t)n * 128;
  float* adst   = asrc   + (size_t)n * 8;
  int*   rowptr = (int*)(adst + (size_t)n * 8);
  int*   col    = rowptr + n;
  int*   deg    = (int*)aggbuf;
  int*   blksum = deg + n;
  __hip_bfloat16* hb = (__hip_bfloat16*)hbuf;
  unsigned short* gt = (unsigned short*)hbuf + (size_t)n * 128;

  // ---------------- g -> gt (bf16 transposed) ----------------
  gprep_kernel<<<32, 256, 0, stream>>>(g, gt);

  // ---------------- CSR build (by destination, self-loops included) ----------------
  const int nb = (n + 2047) / 2048;
  deg_init_kernel<<<(n + 255) / 256, 256, 0, stream>>>(deg, n);
  deg_count_kernel<<<2048, 256, 0, stream>>>(edst, deg, E, n);
  scan1_kernel<<<nb, 256, 0, stream>>>(deg, rowptr, blksum, n);
  scan2_kernel<<<1, 64, 0, stream>>>(blksum, nb);
  scan3_kernel<<<(n + 255) / 256, 256, 0, stream>>>(rowptr, blksum, n);
  scatter_kernel<<<2048, 256, 0, stream>>>(esrc, edst, rowptr, col, E, n);

  // ---------------- conv1 (heads=8, C=16) ----------------
  feat_kernel<8><<<1024, 256, 0, stream>>>(x, W1, as1, ad1, nullptr, hb, asrc, adst, n);
  agg_csr_kernel<8><<<(n + 3) / 4, 256, 0, stream>>>(rowptr, col, asrc, adst, hb, aggbuf, n);

  // ---------------- conv2 (heads=1, C=128) ----------------
  feat_kernel<1><<<1024, 256, 0, stream>>>(aggbuf, W2, as2, ad2, b1, hb, asrc, adst, n);
  agg_csr_kernel<1><<<(n + 3) / 4, 256, 0, stream>>>(rowptr, col, asrc, adst, hb, aggbuf, n);

  // ---------------- h@g + cosine vs mu ----------------
  final_kernel<<<(n + 31) / 32, 256, 0, stream>>>(aggbuf, b2, gt, mu, outp, n);
}

// Round 7
// 467.535 us; speedup vs baseline: 4.9871x; 1.4260x over previous
//
#include <hip/hip_runtime.h>
#include <hip/hip_bf16.h>

typedef short short8 __attribute__((ext_vector_type(8)));
typedef float f32x4 __attribute__((ext_vector_type(4)));

__device__ __forceinline__ float lrelu(float x, float s) { return x > 0.f ? x : x * s; }

__device__ __forceinline__ unsigned short f2bf(float x) {
  union { __hip_bfloat16 b; unsigned short u; } cv;
  cv.b = __float2bfloat16(x);
  return cv.u;
}
__device__ __forceinline__ float bf2f(unsigned short u) {
  return __uint_as_float(((unsigned int)u) << 16);
}

// ---------------- CSR build ----------------
__global__ void deg_init_kernel(int* __restrict__ deg, int n) {
  int i = blockIdx.x * blockDim.x + threadIdx.x;
  if (i < n) deg[i] = 1;   // self-loop
}

// XCD-local counting: group = bid&3 handles dst in [lo,hi)
__global__ void __launch_bounds__(256)
deg_count_kernel(const int* __restrict__ edst, int* __restrict__ deg, int E, int n) {
  const int grp = blockIdx.x & 3;
  const int lo = (int)(((long long)n * grp) >> 2);
  const int hi = (int)(((long long)n * (grp + 1)) >> 2);
  const int tid = (blockIdx.x >> 2) * blockDim.x + threadIdx.x;
  const int stride = (gridDim.x >> 2) * blockDim.x;
  for (int i = tid; i < E; i += stride) {
    const int d = edst[i];
    if (d >= lo && d < hi) atomicAdd(&deg[d], 1);
  }
}

__global__ void __launch_bounds__(256)
scan1_kernel(const int* __restrict__ deg, int* __restrict__ out,
             int* __restrict__ blksum, int n) {
  __shared__ int ts[256];
  const int t = threadIdx.x;
  const int base = blockIdx.x * 2048 + t * 8;
  int v[8]; int s = 0;
  #pragma unroll
  for (int i = 0; i < 8; ++i) {
    int x = (base + i < n) ? deg[base + i] : 0;
    v[i] = s; s += x;
  }
  ts[t] = s;
  __syncthreads();
  for (int off = 1; off < 256; off <<= 1) {
    int add = (t >= off) ? ts[t - off] : 0;
    __syncthreads();
    ts[t] += add;
    __syncthreads();
  }
  const int excl = ts[t] - s;
  #pragma unroll
  for (int i = 0; i < 8; ++i)
    if (base + i < n) out[base + i] = excl + v[i];
  if (t == 255) blksum[blockIdx.x] = ts[255];
}

__global__ void scan2_kernel(int* __restrict__ blksum, int nb) {
  const int t = threadIdx.x;
  int v = (t < nb) ? blksum[t] : 0;
  #pragma unroll
  for (int off = 1; off < 64; off <<= 1) {
    int u = __shfl_up(v, off);
    if (t >= off) v += u;
  }
  if (t < nb) blksum[t] = v;
}

__global__ void scan3_kernel(int* __restrict__ out, const int* __restrict__ blksum, int n) {
  int i = blockIdx.x * blockDim.x + threadIdx.x;
  if (i >= n) return;
  int b = i >> 11;
  if (b > 0) out[i] += blksum[b - 1];
}

// XCD-local scatter
__global__ void __launch_bounds__(256)
scatter_kernel(const int* __restrict__ esrc, const int* __restrict__ edst,
               int* __restrict__ rowptr, int* __restrict__ col,
               int E, int n) {
  const int grp = blockIdx.x & 3;
  const int lo = (int)(((long long)n * grp) >> 2);
  const int hi = (int)(((long long)n * (grp + 1)) >> 2);
  const int tid = (blockIdx.x >> 2) * blockDim.x + threadIdx.x;
  const int stride = (gridDim.x >> 2) * blockDim.x;
  const int Etot = E + n;
  for (int i = tid; i < Etot; i += stride) {
    int s, d;
    if (i < E) { s = esrc[i]; d = edst[i]; } else { s = d = i - E; }
    if (d >= lo && d < hi) {
      int p = atomicAdd(&rowptr[d], 1);
      col[p] = s;
    }
  }
}

// ---------------- g -> gt (bf16, transposed [512][128]) ----------------
__global__ void __launch_bounds__(256)
gprep_kernel(const float* __restrict__ g, unsigned short* __restrict__ gt) {
  __shared__ float ts[32][68];
  const int t = threadIdx.x;
  const int kb = (blockIdx.x >> 3) * 32;
  const int cb = (blockIdx.x & 7) * 64;
  {
    const int r = t >> 3;
    const int c = (t & 7) * 8;
    float4 v0 = *(const float4*)&g[(size_t)(kb + r) * 512 + cb + c];
    float4 v1 = *(const float4*)&g[(size_t)(kb + r) * 512 + cb + c + 4];
    *(float4*)&ts[r][c] = v0;
    *(float4*)&ts[r][c + 4] = v1;
  }
  __syncthreads();
  {
    const int c = t >> 2;
    const int k0 = (t & 3) * 8;
    unsigned short pk[8];
    #pragma unroll
    for (int j = 0; j < 8; ++j) pk[j] = f2bf(ts[k0 + j][c]);
    *(short8*)&gt[(size_t)(cb + c) * 128 + kb + k0] = *(short8*)pk;
  }
}

// ---------------- W -> wt (bf16 transposed) + vt = [W@att_s | W@att_d] ----------------
// grid: 128 blocks (one per k), 128 threads (one per c)
template<int HEADS>
__global__ void __launch_bounds__(128)
wprep_kernel(const float* __restrict__ W, const float* __restrict__ as,
             const float* __restrict__ ad,
             unsigned short* __restrict__ wt, unsigned short* __restrict__ vt)
{
  __shared__ float ss[128], sd[128];
  const int k = blockIdx.x;
  const int c = threadIdx.x;
  const float wv = W[k * 128 + c];
  wt[c * 128 + k] = f2bf(wv);
  ss[c] = wv * as[c];
  sd[c] = wv * ad[c];
  __syncthreads();
  if (c < 16) {
    const int C = 128 / HEADS;
    const int h = (c < 8) ? c : c - 8;
    float s = 0.f;
    if (h < HEADS) {
      const float* sb = (c < 8) ? ss : sd;
      for (int j = 0; j < C; ++j) s += sb[h * C + j];
    }
    vt[c * 128 + k] = f2bf(s);
  }
}

// ---------------- features + attention dots (bf16 MFMA) ----------------
// block 256 = 4 waves; 64 nodes/block, 16/wave. B-tiles: 8 of wt + 1 of vt (dots).
// MFMA 16x16x32: A row=l15,k=lg*8+j ; B col=l15,k=lg*8+j ; C col=l15,row=lg*4+r.
template<int HEADS, bool BF16IN>
__global__ void __launch_bounds__(256)
feat_mfma_kernel(const void* __restrict__ In_, const unsigned short* __restrict__ wt,
                 const unsigned short* __restrict__ vt, const float* __restrict__ bias_in,
                 unsigned short* __restrict__ Hout, float* __restrict__ a_src,
                 float* __restrict__ a_dst, int n)
{
  __shared__ unsigned short xs[64][136];
  const int t = threadIdx.x;
  const int w = t >> 6, lane = t & 63;
  const int l15 = lane & 15, lg = lane >> 4;
  const int nbase = blockIdx.x << 6;

  // stage input -> bf16 LDS (conv2: lrelu(in + b1))
  {
    const int r = t >> 2;
    const int c0s = (t & 3) << 5;
    const int node = nbase + r;
    if (BF16IN) {
      const unsigned short* In2 = (const unsigned short*)In_;
      #pragma unroll
      for (int i = 0; i < 4; ++i) {
        unsigned short pk[8];
        if (node < n) {
          short8 v = *(const short8*)&In2[(size_t)node * 128 + c0s + i * 8];
          #pragma unroll
          for (int j = 0; j < 8; ++j) {
            float f = bf2f((unsigned short)v[j]) + bias_in[c0s + i * 8 + j];
            pk[j] = f2bf(lrelu(f, 0.01f));
          }
        } else {
          #pragma unroll
          for (int j = 0; j < 8; ++j) pk[j] = 0;
        }
        *(short8*)&xs[r][c0s + i * 8] = *(short8*)pk;
      }
    } else {
      const float* In1 = (const float*)In_;
      #pragma unroll
      for (int i = 0; i < 8; ++i) {
        unsigned short pk[4];
        if (node < n) {
          float4 v = *(const float4*)&In1[(size_t)node * 128 + c0s + i * 4];
          pk[0] = f2bf(v.x); pk[1] = f2bf(v.y); pk[2] = f2bf(v.z); pk[3] = f2bf(v.w);
        } else { pk[0] = pk[1] = pk[2] = pk[3] = 0; }
        *(uint2*)&xs[r][c0s + i * 4] = *(uint2*)pk;
      }
    }
  }
  __syncthreads();

  short8 afr[4];
  #pragma unroll
  for (int kc = 0; kc < 4; ++kc)
    afr[kc] = *(const short8*)&xs[w * 16 + l15][kc * 32 + lg * 8];

  const unsigned short* bp[9];
  #pragma unroll
  for (int ct = 0; ct < 8; ++ct)
    bp[ct] = wt + (size_t)(ct * 16 + l15) * 128 + lg * 8;
  bp[8] = vt + (size_t)l15 * 128 + lg * 8;

  f32x4 acc[9];
  #pragma unroll
  for (int ct = 0; ct < 9; ++ct) acc[ct] = (f32x4){0.f, 0.f, 0.f, 0.f};

  short8 bcur[9], bnxt[9];
  #pragma unroll
  for (int ct = 0; ct < 9; ++ct) bcur[ct] = *(const short8*)bp[ct];

  #pragma unroll
  for (int kc = 0; kc < 4; ++kc) {
    if (kc < 3) {
      #pragma unroll
      for (int ct = 0; ct < 9; ++ct)
        bnxt[ct] = *(const short8*)(bp[ct] + (kc + 1) * 32);
    }
    #pragma unroll
    for (int ct = 0; ct < 9; ++ct)
      acc[ct] = __builtin_amdgcn_mfma_f32_16x16x32_bf16(afr[kc], bcur[ct], acc[ct], 0, 0, 0);
    if (kc < 3) {
      #pragma unroll
      for (int ct = 0; ct < 9; ++ct) bcur[ct] = bnxt[ct];
    }
  }
  __syncthreads();   // all A-frag reads complete before xs reuse

  // restage H (bf16) into xs
  #pragma unroll
  for (int ct = 0; ct < 8; ++ct)
    #pragma unroll
    for (int r = 0; r < 4; ++r)
      xs[w * 16 + lg * 4 + r][ct * 16 + l15] = f2bf(acc[ct][r]);
  __syncthreads();

  // coalesced H store
  {
    const int r = t >> 2;
    const int c0s = (t & 3) << 5;
    const int node = nbase + r;
    if (node < n) {
      #pragma unroll
      for (int i = 0; i < 4; ++i)
        *(short8*)&Hout[(size_t)node * 128 + c0s + i * 8] = *(const short8*)&xs[r][c0s + i * 8];
    }
  }
  // dots from the vt tile: col l15<8 -> a_src head l15 ; l15>=8 -> a_dst head l15-8
  #pragma unroll
  for (int r = 0; r < 4; ++r) {
    const int node = nbase + w * 16 + lg * 4 + r;
    if (node < n) {
      const float v = acc[8][r];
      if (HEADS == 8) {
        if (l15 < 8) a_src[node * 8 + l15] = v;
        else         a_dst[node * 8 + (l15 - 8)] = v;
      } else {
        if (l15 == 0) a_src[node] = v;
        else if (l15 == 8) a_dst[node] = v;
      }
    }
  }
}

// ---------------- CSR gather-aggregate (single-pass softmax, batched gathers) ----------------
// one wave per dst; 8-edge batches: 8 independent row-gathers in flight per wave.
template<int HEADS>
__global__ void __launch_bounds__(256)
agg_csr_kernel(const int* __restrict__ rowptr_end, const int* __restrict__ col,
               const float* __restrict__ a_src, const float* __restrict__ a_dst,
               const unsigned short* __restrict__ Hf, unsigned int* __restrict__ agg, int n)
{
  const int wave = threadIdx.x >> 6;
  const int lane = threadIdx.x & 63;
  const int d = blockIdx.x * 4 + wave;
  if (d >= n) return;
  const int beg = (d == 0) ? 0 : rowptr_end[d - 1];
  const int end = rowptr_end[d];

  const int ei = lane >> 3;                       // edge slot 0..7
  const int hh = (HEADS == 8) ? (lane & 7) : 0;   // head this lane computes exp for
  const int bh = (HEADS == 8) ? (lane >> 3) : 0;  // head of this lane's feature pair
  const float adv = (HEADS == 8) ? a_dst[d * 8 + hh] : a_dst[d];
  const unsigned int* Hu = (const unsigned int*)Hf;

  float accx = 0.f, accy = 0.f, sum = 0.f;
  int p0 = beg;
  for (; p0 + 8 <= end; p0 += 8) {
    const int sv = col[p0 + ei];
    const float a = __expf(lrelu(a_src[sv * HEADS + hh] + adv, 0.2f));
    if (HEADS == 8 || (lane & 7) == 0) sum += a;
    int s[8]; float al[8];
    #pragma unroll
    for (int e = 0; e < 8; ++e) {
      s[e]  = __shfl(sv, e * 8);
      al[e] = __shfl(a, e * 8 + bh);
    }
    unsigned int hv[8];
    #pragma unroll
    for (int e = 0; e < 8; ++e) hv[e] = Hu[(size_t)s[e] * 64 + lane];
    #pragma unroll
    for (int e = 0; e < 8; ++e) {
      accx += al[e] * __uint_as_float(hv[e] << 16);
      accy += al[e] * __uint_as_float(hv[e] & 0xffff0000u);
    }
  }
  if (p0 < end) {   // tail < 8
    const int cnt = end - p0;
    int sv = 0; float a = 0.f;
    if (ei < cnt) {
      sv = col[p0 + ei];
      a = __expf(lrelu(a_src[sv * HEADS + hh] + adv, 0.2f));
      if (HEADS == 8 || (lane & 7) == 0) sum += a;
    }
    for (int e = 0; e < cnt; ++e) {
      const float al = __shfl(a, e * 8 + bh);
      const int   s  = __shfl(sv, e * 8);
      const unsigned int hv = Hu[(size_t)s * 64 + lane];
      accx += al * __uint_as_float(hv << 16);
      accy += al * __uint_as_float(hv & 0xffff0000u);
    }
  }
  sum += __shfl_xor(sum, 8);
  sum += __shfl_xor(sum, 16);
  sum += __shfl_xor(sum, 32);
  const float denom = __shfl(sum, (HEADS == 8) ? bh : 0) + 1e-16f;
  const float inv = 1.f / denom;
  accx *= inv; accy *= inv;
  agg[(size_t)d * 64 + lane] = (unsigned int)f2bf(accx) | ((unsigned int)f2bf(accy) << 16);
}

// ---------------- h@g + cosine vs mu (bf16 MFMA GEMM) ----------------
__global__ void __launch_bounds__(256)
final_kernel(const unsigned short* __restrict__ agg2b, const float* __restrict__ b2,
             const unsigned short* __restrict__ gt, const float* __restrict__ mu,
             float* __restrict__ outp, int n)
{
  __shared__ unsigned short os[32][136];
  const int t = threadIdx.x;
  const int w = t >> 6;
  const int lane = t & 63;
  const int l15 = lane & 15;
  const int lg = lane >> 4;
  const int nbase = blockIdx.x << 5;

  {
    const int r = t >> 3;
    const int c = (t & 7) * 16;
    const int node = nbase + r;
    unsigned short pk[16];
    if (node < n) {
      short8 v0 = *(const short8*)&agg2b[(size_t)node * 128 + c];
      short8 v1 = *(const short8*)&agg2b[(size_t)node * 128 + c + 8];
      #pragma unroll
      for (int j = 0; j < 8; ++j) pk[j]     = f2bf(bf2f((unsigned short)v0[j]) + b2[c + j]);
      #pragma unroll
      for (int j = 0; j < 8; ++j) pk[8 + j] = f2bf(bf2f((unsigned short)v1[j]) + b2[c + 8 + j]);
    } else {
      #pragma unroll
      for (int i = 0; i < 16; ++i) pk[i] = 0;
    }
    *(short8*)&os[r][c]     = *(short8*)&pk[0];
    *(short8*)&os[r][c + 8] = *(short8*)&pk[8];
  }
  __syncthreads();

  short8 afr[2][4];
  #pragma unroll
  for (int rt = 0; rt < 2; ++rt)
    #pragma unroll
    for (int kc = 0; kc < 4; ++kc)
      afr[rt][kc] = *(const short8*)&os[rt * 16 + l15][kc * 32 + lg * 8];

  const unsigned short* gw = gt + (size_t)(w * 128 + l15) * 128 + lg * 8;

  f32x4 acc[2][8];
  #pragma unroll
  for (int rt = 0; rt < 2; ++rt)
    #pragma unroll
    for (int ct = 0; ct < 8; ++ct)
      acc[rt][ct] = (f32x4){0.f, 0.f, 0.f, 0.f};

  short8 bcur[8], bnxt[8];
  #pragma unroll
  for (int ct = 0; ct < 8; ++ct)
    bcur[ct] = *(const short8*)&gw[(size_t)ct * 2048];

  #pragma unroll
  for (int kc = 0; kc < 4; ++kc) {
    if (kc < 3) {
      #pragma unroll
      for (int ct = 0; ct < 8; ++ct)
        bnxt[ct] = *(const short8*)&gw[(size_t)ct * 2048 + (kc + 1) * 32];
    }
    #pragma unroll
    for (int ct = 0; ct < 8; ++ct) {
      acc[0][ct] = __builtin_amdgcn_mfma_f32_16x16x32_bf16(afr[0][kc], bcur[ct], acc[0][ct], 0, 0, 0);
      acc[1][ct] = __builtin_amdgcn_mfma_f32_16x16x32_bf16(afr[1][kc], bcur[ct], acc[1][ct], 0, 0, 0);
    }
    if (kc < 3) {
      #pragma unroll
      for (int ct = 0; ct < 8; ++ct) bcur[ct] = bnxt[ct];
    }
  }

  #pragma unroll
  for (int kg = 0; kg < 2; ++kg) {
    const int k = w * 2 + kg;
    float muv[4];
    #pragma unroll
    for (int ct = 0; ct < 4; ++ct) muv[ct] = mu[k * 64 + ct * 16 + l15];
    float mq = 0.f;
    #pragma unroll
    for (int ct = 0; ct < 4; ++ct) mq += muv[ct] * muv[ct];
    mq += __shfl_xor(mq, 1); mq += __shfl_xor(mq, 2);
    mq += __shfl_xor(mq, 4); mq += __shfl_xor(mq, 8);
    const float mun = fmaxf(sqrtf(mq), 1e-8f);
    #pragma unroll
    for (int rt = 0; rt < 2; ++rt) {
      float num[4] = {0.f, 0.f, 0.f, 0.f};
      float ss[4]  = {0.f, 0.f, 0.f, 0.f};
      #pragma unroll
      for (int ct = 0; ct < 4; ++ct) {
        const f32x4 a = acc[rt][kg * 4 + ct];
        #pragma unroll
        for (int r = 0; r < 4; ++r) {
          num[r] += muv[ct] * a[r];
          ss[r]  += a[r] * a[r];
        }
      }
      #pragma unroll
      for (int r = 0; r < 4; ++r) {
        num[r] += __shfl_xor(num[r], 1); ss[r] += __shfl_xor(ss[r], 1);
        num[r] += __shfl_xor(num[r], 2); ss[r] += __shfl_xor(ss[r], 2);
        num[r] += __shfl_xor(num[r], 4); ss[r] += __shfl_xor(ss[r], 4);
        num[r] += __shfl_xor(num[r], 8); ss[r] += __shfl_xor(ss[r], 8);
      }
      if (l15 == 0) {
        #pragma unroll
        for (int r = 0; r < 4; ++r) {
          const int node = nbase + rt * 16 + lg * 4 + r;
          if (node < n) {
            const float den = mun * fmaxf(sqrtf(ss[r]), 1e-8f);
            outp[(size_t)node * 8 + k] = num[r] / den;
          }
        }
      }
    }
  }
}

extern "C" void kernel_launch(void* const* d_in, const int* in_sizes, int n_in,
                              void* d_out, int out_size, void* d_ws, size_t ws_size,
                              hipStream_t stream)
{
  const float* x   = (const float*)d_in[0];
  const int*   eix = (const int*)d_in[1];
  const float* W1  = (const float*)d_in[2];
  const float* as1 = (const float*)d_in[3];
  const float* ad1 = (const float*)d_in[4];
  const float* b1  = (const float*)d_in[5];
  const float* W2  = (const float*)d_in[6];
  const float* as2 = (const float*)d_in[7];
  const float* ad2 = (const float*)d_in[8];
  const float* b2  = (const float*)d_in[9];
  const float* g   = (const float*)d_in[10];
  const float* mu  = (const float*)d_in[11];
  float* outp = (float*)d_out;

  const int n    = in_sizes[0] / 128;
  const int E    = in_sizes[1] / 2;
  const int* esrc = eix;
  const int* edst = eix + E;

  // regions (same boundaries as before):
  //   [0, n*512)        : hb bf16 (n*128) | gt 512x128 | wt1 | vt1 | wt2 | vt2
  //   [n*512, n*1024)   : agg bf16 (n*128) ; deg/blksum alias (CSR phase only)
  //   then asrc, adst (f32, n*8 each), rowptr (n), col (E+n)
  unsigned short* hb  = (unsigned short*)d_ws;
  unsigned short* gt  = hb + (size_t)n * 128;
  unsigned short* wt1 = gt + 512 * 128;
  unsigned short* vt1 = wt1 + 128 * 128;
  unsigned short* wt2 = vt1 + 16 * 128;
  unsigned short* vt2 = wt2 + 128 * 128;
  unsigned short* agg_b = (unsigned short*)((char*)d_ws + (size_t)n * 512);
  float* asrc   = (float*)((char*)d_ws + (size_t)n * 1024);
  float* adst   = asrc + (size_t)n * 8;
  int*   rowptr = (int*)(adst + (size_t)n * 8);
  int*   col    = rowptr + n;
  int*   deg    = (int*)agg_b;
  int*   blksum = deg + n;

  // ---------------- param prep ----------------
  gprep_kernel<<<32, 256, 0, stream>>>(g, gt);
  wprep_kernel<8><<<128, 128, 0, stream>>>(W1, as1, ad1, wt1, vt1);
  wprep_kernel<1><<<128, 128, 0, stream>>>(W2, as2, ad2, wt2, vt2);

  // ---------------- CSR build (by destination, self-loops included) ----------------
  const int nb = (n + 2047) / 2048;
  deg_init_kernel<<<(n + 255) / 256, 256, 0, stream>>>(deg, n);
  deg_count_kernel<<<2048, 256, 0, stream>>>(edst, deg, E, n);
  scan1_kernel<<<nb, 256, 0, stream>>>(deg, rowptr, blksum, n);
  scan2_kernel<<<1, 64, 0, stream>>>(blksum, nb);
  scan3_kernel<<<(n + 255) / 256, 256, 0, stream>>>(rowptr, blksum, n);
  scatter_kernel<<<2048, 256, 0, stream>>>(esrc, edst, rowptr, col, E, n);

  // ---------------- conv1 (heads=8, C=16) ----------------
  feat_mfma_kernel<8, false><<<(n + 63) / 64, 256, 0, stream>>>(
      x, wt1, vt1, nullptr, hb, asrc, adst, n);
  agg_csr_kernel<8><<<(n + 3) / 4, 256, 0, stream>>>(
      rowptr, col, asrc, adst, hb, (unsigned int*)agg_b, n);

  // ---------------- conv2 (heads=1, C=128) ----------------
  feat_mfma_kernel<1, true><<<(n + 63) / 64, 256, 0, stream>>>(
      agg_b, wt2, vt2, b1, hb, asrc, adst, n);
  agg_csr_kernel<1><<<(n + 3) / 4, 256, 0, stream>>>(
      rowptr, col, asrc, adst, hb, (unsigned int*)agg_b, n);

  // ---------------- h@g + cosine vs mu ----------------
  final_kernel<<<(n + 31) / 32, 256, 0, stream>>>(agg_b, b2, gt, mu, outp, n);
}